// Round 1
// baseline (5620.126 us; speedup 1.0000x reference)
//
#include <hip/hip_runtime.h>
#include <cmath>

#define EPSBN 1e-5f

// ---------------- utility kernels ----------------
__global__ __launch_bounds__(256) void k_count_deg(const int* __restrict__ dst, int* __restrict__ deg, int E) {
  int i = blockIdx.x * 256 + threadIdx.x;
  if (i < E) atomicAdd(&deg[dst[i]], 1);
}

__global__ __launch_bounds__(256) void k_make_dis(const int* __restrict__ deg, float* __restrict__ dis, int N) {
  int i = blockIdx.x * 256 + threadIdx.x;
  if (i < N) dis[i] = rsqrtf((float)(deg[i] + 1));  // +1 self-loop
}

__global__ __launch_bounds__(256) void k_transpose(const float* __restrict__ W, float* __restrict__ WT, int R, int C) {
  int i = blockIdx.x * 256 + threadIdx.x;
  if (i < R * C) { int r = i / C, c = i - r * C; WT[(size_t)c * R + r] = W[i]; }
}

// ---------------- matmul: C[N,M] = A[N,K] @ B[K,M] (+bias)(relu) ----------------
// 64x64 tile, K-step 16, 256 threads, 4x4 accum per thread
__global__ __launch_bounds__(256) void k_mm(const float* __restrict__ A, const float* __restrict__ B,
                                            const float* __restrict__ bias, float* __restrict__ C,
                                            int N, int K, int M, int relu)
{
  __shared__ float As[64][20];   // padded: 2-way max bank conflict, 16B-aligned f4 stores
  __shared__ float Bs[16][64];
  int tid = threadIdx.x;
  int brow = blockIdx.y * 64, bcol = blockIdx.x * 64;
  int tr = (tid >> 4) << 2, tc = (tid & 15) << 2;
  int ar = tid >> 2, aq = (tid & 3) << 2;   // A load: row ar (0..63), k-quad aq
  int bk = tid >> 4;                        // B load: k row (0..15), col quad tc
  float acc[4][4] = {{0.f}};
  for (int k0 = 0; k0 < K; k0 += 16) {
    float4 av;
    int arow = brow + ar;
    if (arow < N) av = *(const float4*)(A + (size_t)arow * K + (k0 + aq));
    else av = make_float4(0.f, 0.f, 0.f, 0.f);
    *(float4*)&As[ar][aq] = av;
    *(float4*)&Bs[bk][tc] = *(const float4*)(B + (size_t)(k0 + bk) * M + (bcol + tc));
    __syncthreads();
#pragma unroll
    for (int k = 0; k < 16; ++k) {
      float a0 = As[tr + 0][k], a1 = As[tr + 1][k], a2 = As[tr + 2][k], a3 = As[tr + 3][k];
      float4 b = *(float4*)&Bs[k][tc];
      acc[0][0] = fmaf(a0, b.x, acc[0][0]); acc[0][1] = fmaf(a0, b.y, acc[0][1]);
      acc[0][2] = fmaf(a0, b.z, acc[0][2]); acc[0][3] = fmaf(a0, b.w, acc[0][3]);
      acc[1][0] = fmaf(a1, b.x, acc[1][0]); acc[1][1] = fmaf(a1, b.y, acc[1][1]);
      acc[1][2] = fmaf(a1, b.z, acc[1][2]); acc[1][3] = fmaf(a1, b.w, acc[1][3]);
      acc[2][0] = fmaf(a2, b.x, acc[2][0]); acc[2][1] = fmaf(a2, b.y, acc[2][1]);
      acc[2][2] = fmaf(a2, b.z, acc[2][2]); acc[2][3] = fmaf(a2, b.w, acc[2][3]);
      acc[3][0] = fmaf(a3, b.x, acc[3][0]); acc[3][1] = fmaf(a3, b.y, acc[3][1]);
      acc[3][2] = fmaf(a3, b.z, acc[3][2]); acc[3][3] = fmaf(a3, b.w, acc[3][3]);
    }
    __syncthreads();
  }
  float4 bv = make_float4(0.f, 0.f, 0.f, 0.f);
  if (bias) bv = *(const float4*)(bias + bcol + tc);
#pragma unroll
  for (int i = 0; i < 4; ++i) {
    int row = brow + tr + i;
    if (row >= N) break;
    float4 v;
    v.x = acc[i][0] + bv.x; v.y = acc[i][1] + bv.y;
    v.z = acc[i][2] + bv.z; v.w = acc[i][3] + bv.w;
    if (relu) { v.x = fmaxf(v.x, 0.f); v.y = fmaxf(v.y, 0.f); v.z = fmaxf(v.z, 0.f); v.w = fmaxf(v.w, 0.f); }
    *(float4*)(C + (size_t)row * M + (bcol + tc)) = v;
  }
}

// ---------------- BatchNorm (training-mode batch stats) ----------------
__global__ void k_bn_partial(const float* __restrict__ x, int N, int D,
                             float* __restrict__ ps, float* __restrict__ pss) {
  int c = threadIdx.x;  // blockDim.x == D
  float s = 0.f, ss = 0.f;
  for (int r = blockIdx.x; r < N; r += gridDim.x) {
    float v = x[(size_t)r * D + c];
    s += v; ss += v * v;
  }
  ps[(size_t)blockIdx.x * D + c] = s;
  pss[(size_t)blockIdx.x * D + c] = ss;
}

__global__ void k_bn_finalize(const float* __restrict__ ps, const float* __restrict__ pss,
                              int NB, int D, float invN,
                              const float* __restrict__ gamma, const float* __restrict__ beta,
                              float* __restrict__ coef) {
  int c = threadIdx.x;  // blockDim.x == D
  float s = 0.f, ss = 0.f;
  for (int b = 0; b < NB; ++b) { s += ps[(size_t)b * D + c]; ss += pss[(size_t)b * D + c]; }
  float mean = s * invN;
  float var = ss * invN - mean * mean;   // biased variance
  float a = gamma[c] * rsqrtf(var + EPSBN);
  coef[c] = a;
  coef[D + c] = beta[c] - mean * a;
}

// mode: 0 y=bn(x); 1 y=bn(x), mx=max(mx,y); 2 y=relu(bn(x)); 3 y=bn(x), mx=y
__global__ __launch_bounds__(256) void k_bn_apply(const float* __restrict__ x, const float* __restrict__ coef,
                                                  float* __restrict__ y, float* __restrict__ mx,
                                                  int total, int Dmask, int D, int mode) {
  int i = blockIdx.x * 256 + threadIdx.x;
  if (i >= total) return;
  int f = i & Dmask;
  float v = x[i] * coef[f] + coef[D + f];
  if (mode == 2) v = fmaxf(v, 0.f);
  y[i] = v;
  if (mode == 1) mx[i] = fmaxf(mx[i], v);
  else if (mode == 3) mx[i] = v;
}

// ---------------- GCN ----------------
__global__ __launch_bounds__(256) void k_gcn_init(const float* __restrict__ hp, const float* __restrict__ dis,
                                                  const float* __restrict__ bg, float* __restrict__ c, int total) {
  int i = blockIdx.x * 256 + threadIdx.x;
  if (i >= total) return;
  int n = i >> 7, f = i & 127;
  float d = dis[n];
  c[i] = bg[f] + d * d * hp[i];   // self-loop term + bias
}

__global__ __launch_bounds__(256) void k_gcn_scatter(const int* __restrict__ src, const int* __restrict__ dst,
                                                     const float* __restrict__ dis, const float* __restrict__ hp,
                                                     float* __restrict__ c, int E) {
  int t = blockIdx.x * 256 + threadIdx.x;
  int e = t >> 5, lane = t & 31;
  if (e >= E) return;
  int s = src[e], d = dst[e];
  float nrm = dis[s] * dis[d];
  float4 v = *(const float4*)(hp + ((size_t)s << 7) + (lane << 2));
  float* crow = c + ((size_t)d << 7) + (lane << 2);
  atomicAdd(crow + 0, nrm * v.x);
  atomicAdd(crow + 1, nrm * v.y);
  atomicAdd(crow + 2, nrm * v.z);
  atomicAdd(crow + 3, nrm * v.w);
}

// ---------------- GRU gates ----------------
__global__ __launch_bounds__(256) void k_gru_gates(const float* __restrict__ gi, const float* __restrict__ gh,
                                                   const float* __restrict__ c, float* __restrict__ hn, int total) {
  int i = blockIdx.x * 256 + threadIdx.x;
  if (i >= total) return;
  int n = i >> 7, f = i & 127;
  size_t base = (size_t)n * 384 + f;
  float ir = gi[base], iz = gi[base + 128], in_ = gi[base + 256];
  float hr = gh[base], hz = gh[base + 128], hn_ = gh[base + 256];
  float cv = c[i];
  float r = 1.f / (1.f + expf(-(ir + hr)));
  float z = 1.f / (1.f + expf(-(iz + hz)));
  float nn = tanhf(in_ + r * hn_);
  hn[i] = (1.f - z) * nn + z * cv;
}

// ---------------- final matvec: out = y2 @ W2 + b2 ----------------
__global__ __launch_bounds__(256) void k_matvec(const float* __restrict__ y, const float* __restrict__ W2,
                                                const float* __restrict__ b2, float* __restrict__ out, int N) {
  int t = blockIdx.x * 256 + threadIdx.x;
  int row = t >> 6, lane = t & 63;
  if (row >= N) return;
  const float* yr = y + (size_t)row * 256;
  float s = 0.f;
#pragma unroll
  for (int k = 0; k < 4; ++k) s += yr[lane + 64 * k] * W2[lane + 64 * k];
#pragma unroll
  for (int off = 32; off > 0; off >>= 1) s += __shfl_down(s, off);
  if (lane == 0) out[row] = s + b2[0];
}

// ---------------- host orchestration ----------------
static void bn_stats(const float* x, int N, int D, const float* gamma, const float* beta,
                     float* ps, float* pss, float* coef, hipStream_t stream) {
  const int NB = 256;
  k_bn_partial<<<NB, D, 0, stream>>>(x, N, D, ps, pss);
  k_bn_finalize<<<1, D, 0, stream>>>(ps, pss, NB, D, 1.0f / (float)N, gamma, beta, coef);
}

extern "C" void kernel_launch(void* const* d_in, const int* in_sizes, int n_in,
                              void* d_out, int out_size, void* d_ws, size_t ws_size,
                              hipStream_t stream) {
  const float* x    = (const float*)d_in[0];
  const int*   ei   = (const int*)d_in[1];
  const float* W_in = (const float*)d_in[2];
  const float* b_in = (const float*)d_in[3];
  const float* g0   = (const float*)d_in[4];
  const float* be0  = (const float*)d_in[5];
  const float* W_g  = (const float*)d_in[6];
  const float* b_g  = (const float*)d_in[7];
  const float* W_ih = (const float*)d_in[8];
  const float* W_hh = (const float*)d_in[9];
  const float* b_ih = (const float*)d_in[10];
  const float* b_hh = (const float*)d_in[11];
  const float* g_c  = (const float*)d_in[12];
  const float* be_c = (const float*)d_in[13];
  const float* g_o  = (const float*)d_in[14];
  const float* be_o = (const float*)d_in[15];
  const float* W1   = (const float*)d_in[16];
  const float* b1   = (const float*)d_in[17];
  const float* g1   = (const float*)d_in[18];
  const float* be1  = (const float*)d_in[19];
  const float* W2   = (const float*)d_in[20];
  const float* b2   = (const float*)d_in[21];

  const int N = in_sizes[0] / 128;   // 30000
  const int E = in_sizes[1] / 2;     // 480000
  const int ND = N * 128;
  const int NH = N * 256;

  float* p    = (float*)d_ws;
  float* h    = p; p += ND;
  float* mx   = p; p += ND;
  float* hp   = p; p += ND;
  float* cb   = p; p += ND;
  float* gi   = p; p += (size_t)N * 384;
  float* gh   = p; p += (size_t)N * 384;
  float* WihT = p; p += 384 * 128;
  float* WhhT = p; p += 384 * 128;
  float* dis  = p; p += ((N + 255) & ~255);
  float* ps   = p; p += 256 * 256;
  float* pss  = p; p += 256 * 256;
  float* coef = p; p += 512;
  int*   degi = (int*)p;

  dim3 blk(256);
  int ew  = (ND + 255) / 256;
  int ew2 = (NH + 255) / 256;
  int rowblocks = (N + 63) / 64;

  hipMemsetAsync(degi, 0, (size_t)N * sizeof(int), stream);
  k_count_deg<<<(E + 255) / 256, blk, 0, stream>>>(ei + E, degi, E);
  k_make_dis<<<(N + 255) / 256, blk, 0, stream>>>(degi, dis, N);
  k_transpose<<<(384 * 128 + 255) / 256, blk, 0, stream>>>(W_ih, WihT, 384, 128);
  k_transpose<<<(384 * 128 + 255) / 256, blk, 0, stream>>>(W_hh, WhhT, 384, 128);

  // input layer: h = BN(relu(x @ W_in + b_in)); mx = h
  k_mm<<<dim3(2, rowblocks), blk, 0, stream>>>(x, W_in, b_in, hp, N, 128, 128, 1);
  bn_stats(hp, N, 128, g0, be0, ps, pss, coef, stream);
  k_bn_apply<<<ew, blk, 0, stream>>>(hp, coef, h, mx, ND, 127, 128, 3);

  for (int it = 0; it < 5; ++it) {
    // GCN: cb = b_g + scatter(norm * (h @ W_g))
    k_mm<<<dim3(2, rowblocks), blk, 0, stream>>>(h, W_g, nullptr, hp, N, 128, 128, 0);
    k_gcn_init<<<ew, blk, 0, stream>>>(hp, dis, b_g, cb, ND);
    k_gcn_scatter<<<(E * 32 + 255) / 256, blk, 0, stream>>>(ei, ei + E, dis, hp, cb, E);
    // GRU(inp=h, hid=cb)
    k_mm<<<dim3(6, rowblocks), blk, 0, stream>>>(h,  WihT, b_ih, gi, N, 128, 384, 0);
    k_mm<<<dim3(6, rowblocks), blk, 0, stream>>>(cb, WhhT, b_hh, gh, N, 128, 384, 0);
    k_gru_gates<<<ew, blk, 0, stream>>>(gi, gh, cb, hp, ND);
    // BN + running max
    bn_stats(hp, N, 128, g_c, be_c, ps, pss, coef, stream);
    k_bn_apply<<<ew, blk, 0, stream>>>(hp, coef, h, mx, ND, 127, 128, 1);
  }

  // output BN -> encoder
  bn_stats(mx, N, 128, g_o, be_o, ps, pss, coef, stream);
  k_bn_apply<<<ew, blk, 0, stream>>>(mx, coef, cb, nullptr, ND, 127, 128, 0);
  k_mm<<<dim3(4, rowblocks), blk, 0, stream>>>(cb, W1, b1, gi, N, 128, 256, 0);
  bn_stats(gi, N, 256, g1, be1, ps, pss, coef, stream);
  k_bn_apply<<<ew2, blk, 0, stream>>>(gi, coef, gh, nullptr, NH, 255, 256, 2);
  k_matvec<<<(N * 64 + 255) / 256, blk, 0, stream>>>(gh, W2, b2, (float*)d_out, N);
}

// Round 2
// 1837.658 us; speedup vs baseline: 3.0583x; 3.0583x over previous
//
#include <hip/hip_runtime.h>
#include <cmath>

#define EPSBN 1e-5f

// ---------------- utility kernels ----------------
__global__ __launch_bounds__(256) void k_count_deg(const int* __restrict__ dst, int* __restrict__ deg, int E) {
  int i = blockIdx.x * 256 + threadIdx.x;
  if (i < E) atomicAdd(&deg[dst[i]], 1);
}

__global__ __launch_bounds__(256) void k_make_dis(const int* __restrict__ deg, float* __restrict__ dis, int N) {
  int i = blockIdx.x * 256 + threadIdx.x;
  if (i < N) dis[i] = rsqrtf((float)(deg[i] + 1));  // +1 self-loop
}

__global__ __launch_bounds__(256) void k_transpose(const float* __restrict__ W, float* __restrict__ WT, int R, int C) {
  int i = blockIdx.x * 256 + threadIdx.x;
  if (i < R * C) { int r = i / C, c = i - r * C; WT[(size_t)c * R + r] = W[i]; }
}

// exclusive scan of deg[0..N) -> rowptr[0..N], also fills cursor = rowptr
__global__ void k_scan(const int* __restrict__ deg, int* __restrict__ rowptr,
                       int* __restrict__ cursor, int N) {
  __shared__ int sums[256];
  int t = threadIdx.x;
  int chunk = (N + 255) / 256;
  int beg = t * chunk, end = min(beg + chunk, N);
  int s = 0;
  for (int i = beg; i < end; ++i) s += deg[i];
  sums[t] = s;
  __syncthreads();
  for (int off = 1; off < 256; off <<= 1) {
    int v = (t >= off) ? sums[t - off] : 0;
    __syncthreads();
    sums[t] += v;
    __syncthreads();
  }
  int run = (t == 0) ? 0 : sums[t - 1];
  for (int i = beg; i < end; ++i) {
    rowptr[i] = run;
    cursor[i] = run;
    run += deg[i];
  }
  if (t == 255) rowptr[N] = run;
}

__global__ __launch_bounds__(256) void k_csr_fill(const int* __restrict__ src, const int* __restrict__ dst,
                                                  const float* __restrict__ dis, int* __restrict__ cursor,
                                                  int* __restrict__ csr_src, float* __restrict__ csr_nrm, int E) {
  int e = blockIdx.x * 256 + threadIdx.x;
  if (e >= E) return;
  int s = src[e], d = dst[e];
  int pos = atomicAdd(&cursor[d], 1);
  csr_src[pos] = s;
  csr_nrm[pos] = dis[s] * dis[d];
}

// ---------------- matmul: C[N,M] = A[N,K] @ B[K,M] (+bias)(relu) ----------------
// 64x64 tile, K-step 16, 256 threads, 4x4 accum; As is k-major so the inner
// loop is one ds_read_b128 per operand (was 4x ds_read_b32 + 1x b128).
__global__ __launch_bounds__(256) void k_mm(const float* __restrict__ A, const float* __restrict__ B,
                                            const float* __restrict__ bias, float* __restrict__ C,
                                            int N, int K, int M, int relu)
{
  __shared__ float As[16][68];   // [k][row], pad 68 -> 2-way write conflicts max (free)
  __shared__ float Bs[16][64];
  int tid = threadIdx.x;
  int brow = blockIdx.y * 64, bcol = blockIdx.x * 64;
  int tr = (tid >> 4) << 2, tc = (tid & 15) << 2;
  int ar = tid >> 2, aq = (tid & 3) << 2;   // A load: row ar (0..63), k-quad aq
  int bk = tid >> 4;                        // B load: k row (0..15), col quad tc
  float acc[4][4] = {{0.f}};
  for (int k0 = 0; k0 < K; k0 += 16) {
    float4 av = make_float4(0.f, 0.f, 0.f, 0.f);
    int arow = brow + ar;
    if (arow < N) av = *(const float4*)(A + (size_t)arow * K + (k0 + aq));
    As[aq + 0][ar] = av.x; As[aq + 1][ar] = av.y;
    As[aq + 2][ar] = av.z; As[aq + 3][ar] = av.w;
    *(float4*)&Bs[bk][tc] = *(const float4*)(B + (size_t)(k0 + bk) * M + (bcol + tc));
    __syncthreads();
#pragma unroll
    for (int k = 0; k < 16; ++k) {
      float4 a = *(float4*)&As[k][tr];
      float4 b = *(float4*)&Bs[k][tc];
      acc[0][0] = fmaf(a.x, b.x, acc[0][0]); acc[0][1] = fmaf(a.x, b.y, acc[0][1]);
      acc[0][2] = fmaf(a.x, b.z, acc[0][2]); acc[0][3] = fmaf(a.x, b.w, acc[0][3]);
      acc[1][0] = fmaf(a.y, b.x, acc[1][0]); acc[1][1] = fmaf(a.y, b.y, acc[1][1]);
      acc[1][2] = fmaf(a.y, b.z, acc[1][2]); acc[1][3] = fmaf(a.y, b.w, acc[1][3]);
      acc[2][0] = fmaf(a.z, b.x, acc[2][0]); acc[2][1] = fmaf(a.z, b.y, acc[2][1]);
      acc[2][2] = fmaf(a.z, b.z, acc[2][2]); acc[2][3] = fmaf(a.z, b.w, acc[2][3]);
      acc[3][0] = fmaf(a.w, b.x, acc[3][0]); acc[3][1] = fmaf(a.w, b.y, acc[3][1]);
      acc[3][2] = fmaf(a.w, b.z, acc[3][2]); acc[3][3] = fmaf(a.w, b.w, acc[3][3]);
    }
    __syncthreads();
  }
  float4 bv = make_float4(0.f, 0.f, 0.f, 0.f);
  if (bias) bv = *(const float4*)(bias + bcol + tc);
#pragma unroll
  for (int i = 0; i < 4; ++i) {
    int row = brow + tr + i;
    if (row >= N) break;
    float4 v;
    v.x = acc[i][0] + bv.x; v.y = acc[i][1] + bv.y;
    v.z = acc[i][2] + bv.z; v.w = acc[i][3] + bv.w;
    if (relu) { v.x = fmaxf(v.x, 0.f); v.y = fmaxf(v.y, 0.f); v.z = fmaxf(v.z, 0.f); v.w = fmaxf(v.w, 0.f); }
    *(float4*)(C + (size_t)row * M + (bcol + tc)) = v;
  }
}

// ---------------- BatchNorm (training-mode batch stats) ----------------
__global__ void k_bn_partial(const float* __restrict__ x, int N, int D,
                             float* __restrict__ ps, float* __restrict__ pss) {
  int c = threadIdx.x;  // blockDim.x == D
  float s = 0.f, ss = 0.f;
  for (int r = blockIdx.x; r < N; r += gridDim.x) {
    float v = x[(size_t)r * D + c];
    s += v; ss += v * v;
  }
  ps[(size_t)blockIdx.x * D + c] = s;
  pss[(size_t)blockIdx.x * D + c] = ss;
}

__global__ void k_bn_finalize(const float* __restrict__ ps, const float* __restrict__ pss,
                              int NB, int D, float invN,
                              const float* __restrict__ gamma, const float* __restrict__ beta,
                              float* __restrict__ coef) {
  int c = threadIdx.x;  // blockDim.x == D
  float s = 0.f, ss = 0.f;
  for (int b = 0; b < NB; ++b) { s += ps[(size_t)b * D + c]; ss += pss[(size_t)b * D + c]; }
  float mean = s * invN;
  float var = ss * invN - mean * mean;   // biased variance
  float a = gamma[c] * rsqrtf(var + EPSBN);
  coef[c] = a;
  coef[D + c] = beta[c] - mean * a;
}

// mode: 0 y=bn(x); 1 y=bn(x), mx=max(mx,y); 2 y=relu(bn(x)); 3 y=bn(x), mx=y
__global__ __launch_bounds__(256) void k_bn_apply(const float* __restrict__ x, const float* __restrict__ coef,
                                                  float* __restrict__ y, float* __restrict__ mx,
                                                  int total, int Dmask, int D, int mode) {
  int i = blockIdx.x * 256 + threadIdx.x;
  if (i >= total) return;
  int f = i & Dmask;
  float v = x[i] * coef[f] + coef[D + f];
  if (mode == 2) v = fmaxf(v, 0.f);
  y[i] = v;
  if (mode == 1) mx[i] = fmaxf(mx[i], v);
  else if (mode == 3) mx[i] = v;
}

// ---------------- GCN gather (CSR, no atomics) ----------------
// one 32-lane group per dst node; includes bias + self-loop term
__global__ __launch_bounds__(256) void k_gcn_gather(const int* __restrict__ rowptr, const int* __restrict__ csr_src,
                                                    const float* __restrict__ csr_nrm, const float* __restrict__ dis,
                                                    const float* __restrict__ hp, const float* __restrict__ bg,
                                                    float* __restrict__ c, int N) {
  int t = blockIdx.x * 256 + threadIdx.x;
  int g = t >> 5, lane = t & 31;
  if (g >= N) return;
  int off = lane << 2;
  float dd = dis[g];
  float w0 = dd * dd;
  float4 acc = *(const float4*)(bg + off);
  float4 hv = *(const float4*)(hp + ((size_t)g << 7) + off);
  acc.x += w0 * hv.x; acc.y += w0 * hv.y; acc.z += w0 * hv.z; acc.w += w0 * hv.w;
  int beg = rowptr[g], end = rowptr[g + 1];
  int j = beg;
  for (; j + 1 < end; j += 2) {
    int s0 = csr_src[j], s1 = csr_src[j + 1];
    float n0 = csr_nrm[j], n1 = csr_nrm[j + 1];
    float4 v0 = *(const float4*)(hp + ((size_t)s0 << 7) + off);
    float4 v1 = *(const float4*)(hp + ((size_t)s1 << 7) + off);
    acc.x += n0 * v0.x + n1 * v1.x;
    acc.y += n0 * v0.y + n1 * v1.y;
    acc.z += n0 * v0.z + n1 * v1.z;
    acc.w += n0 * v0.w + n1 * v1.w;
  }
  if (j < end) {
    int s0 = csr_src[j];
    float n0 = csr_nrm[j];
    float4 v0 = *(const float4*)(hp + ((size_t)s0 << 7) + off);
    acc.x += n0 * v0.x; acc.y += n0 * v0.y; acc.z += n0 * v0.z; acc.w += n0 * v0.w;
  }
  *(float4*)(c + ((size_t)g << 7) + off) = acc;
}

// ---------------- GRU gates ----------------
__global__ __launch_bounds__(256) void k_gru_gates(const float* __restrict__ gi, const float* __restrict__ gh,
                                                   const float* __restrict__ c, float* __restrict__ hn, int total) {
  int i = blockIdx.x * 256 + threadIdx.x;
  if (i >= total) return;
  int n = i >> 7, f = i & 127;
  size_t base = (size_t)n * 384 + f;
  float ir = gi[base], iz = gi[base + 128], in_ = gi[base + 256];
  float hr = gh[base], hz = gh[base + 128], hn_ = gh[base + 256];
  float cv = c[i];
  float r = 1.f / (1.f + expf(-(ir + hr)));
  float z = 1.f / (1.f + expf(-(iz + hz)));
  float nn = tanhf(in_ + r * hn_);
  hn[i] = (1.f - z) * nn + z * cv;
}

// ---------------- final matvec: out = y2 @ W2 + b2 ----------------
__global__ __launch_bounds__(256) void k_matvec(const float* __restrict__ y, const float* __restrict__ W2,
                                                const float* __restrict__ b2, float* __restrict__ out, int N) {
  int t = blockIdx.x * 256 + threadIdx.x;
  int row = t >> 6, lane = t & 63;
  if (row >= N) return;
  const float* yr = y + (size_t)row * 256;
  float s = 0.f;
#pragma unroll
  for (int k = 0; k < 4; ++k) s += yr[lane + 64 * k] * W2[lane + 64 * k];
#pragma unroll
  for (int off = 32; off > 0; off >>= 1) s += __shfl_down(s, off);
  if (lane == 0) out[row] = s + b2[0];
}

// ---------------- host orchestration ----------------
static void bn_stats(const float* x, int N, int D, const float* gamma, const float* beta,
                     float* ps, float* pss, float* coef, hipStream_t stream) {
  const int NB = 256;
  k_bn_partial<<<NB, D, 0, stream>>>(x, N, D, ps, pss);
  k_bn_finalize<<<1, D, 0, stream>>>(ps, pss, NB, D, 1.0f / (float)N, gamma, beta, coef);
}

extern "C" void kernel_launch(void* const* d_in, const int* in_sizes, int n_in,
                              void* d_out, int out_size, void* d_ws, size_t ws_size,
                              hipStream_t stream) {
  const float* x    = (const float*)d_in[0];
  const int*   ei   = (const int*)d_in[1];
  const float* W_in = (const float*)d_in[2];
  const float* b_in = (const float*)d_in[3];
  const float* g0   = (const float*)d_in[4];
  const float* be0  = (const float*)d_in[5];
  const float* W_g  = (const float*)d_in[6];
  const float* b_g  = (const float*)d_in[7];
  const float* W_ih = (const float*)d_in[8];
  const float* W_hh = (const float*)d_in[9];
  const float* b_ih = (const float*)d_in[10];
  const float* b_hh = (const float*)d_in[11];
  const float* g_c  = (const float*)d_in[12];
  const float* be_c = (const float*)d_in[13];
  const float* g_o  = (const float*)d_in[14];
  const float* be_o = (const float*)d_in[15];
  const float* W1   = (const float*)d_in[16];
  const float* b1   = (const float*)d_in[17];
  const float* g1   = (const float*)d_in[18];
  const float* be1  = (const float*)d_in[19];
  const float* W2   = (const float*)d_in[20];
  const float* b2   = (const float*)d_in[21];

  const int N = in_sizes[0] / 128;   // 30000
  const int E = in_sizes[1] / 2;     // 480000
  const int ND = N * 128;
  const int NH = N * 256;

  float* p    = (float*)d_ws;
  float* h    = p; p += ND;
  float* mx   = p; p += ND;
  float* hp   = p; p += ND;
  float* cb   = p; p += ND;
  float* gi   = p; p += (size_t)N * 384;
  float* gh   = p; p += (size_t)N * 384;
  float* WihT = p; p += 384 * 128;
  float* WhhT = p; p += 384 * 128;
  float* dis  = p; p += ((N + 255) & ~255);
  float* ps   = p; p += 256 * 256;
  float* pss  = p; p += 256 * 256;
  float* coef = p; p += 512;
  float* csr_nrm = p; p += E;
  int*   degi    = (int*)p; p += ((N + 255) & ~255);
  int*   rowptr  = (int*)p; p += ((N + 1 + 255) & ~255);
  int*   cursor  = (int*)p; p += ((N + 255) & ~255);
  int*   csr_src = (int*)p; p += E;

  dim3 blk(256);
  int ew  = (ND + 255) / 256;
  int ew2 = (NH + 255) / 256;
  int rowblocks = (N + 63) / 64;

  // ---- graph preprocessing (once per launch) ----
  hipMemsetAsync(degi, 0, (size_t)N * sizeof(int), stream);
  k_count_deg<<<(E + 255) / 256, blk, 0, stream>>>(ei + E, degi, E);
  k_make_dis<<<(N + 255) / 256, blk, 0, stream>>>(degi, dis, N);
  k_scan<<<1, 256, 0, stream>>>(degi, rowptr, cursor, N);
  k_csr_fill<<<(E + 255) / 256, blk, 0, stream>>>(ei, ei + E, dis, cursor, csr_src, csr_nrm, E);
  k_transpose<<<(384 * 128 + 255) / 256, blk, 0, stream>>>(W_ih, WihT, 384, 128);
  k_transpose<<<(384 * 128 + 255) / 256, blk, 0, stream>>>(W_hh, WhhT, 384, 128);

  // input layer: h = BN(relu(x @ W_in + b_in)); mx = h
  k_mm<<<dim3(2, rowblocks), blk, 0, stream>>>(x, W_in, b_in, hp, N, 128, 128, 1);
  bn_stats(hp, N, 128, g0, be0, ps, pss, coef, stream);
  k_bn_apply<<<ew, blk, 0, stream>>>(hp, coef, h, mx, ND, 127, 128, 3);

  for (int it = 0; it < 5; ++it) {
    // GCN: cb = b_g + selfloop + gather(norm * (h @ W_g))
    k_mm<<<dim3(2, rowblocks), blk, 0, stream>>>(h, W_g, nullptr, hp, N, 128, 128, 0);
    k_gcn_gather<<<(N * 32 + 255) / 256, blk, 0, stream>>>(rowptr, csr_src, csr_nrm, dis, hp, b_g, cb, N);
    // GRU(inp=h, hid=cb)
    k_mm<<<dim3(6, rowblocks), blk, 0, stream>>>(h,  WihT, b_ih, gi, N, 128, 384, 0);
    k_mm<<<dim3(6, rowblocks), blk, 0, stream>>>(cb, WhhT, b_hh, gh, N, 128, 384, 0);
    k_gru_gates<<<ew, blk, 0, stream>>>(gi, gh, cb, hp, ND);
    // BN + running max
    bn_stats(hp, N, 128, g_c, be_c, ps, pss, coef, stream);
    k_bn_apply<<<ew, blk, 0, stream>>>(hp, coef, h, mx, ND, 127, 128, 1);
  }

  // output BN -> encoder
  bn_stats(mx, N, 128, g_o, be_o, ps, pss, coef, stream);
  k_bn_apply<<<ew, blk, 0, stream>>>(mx, coef, cb, nullptr, ND, 127, 128, 0);
  k_mm<<<dim3(4, rowblocks), blk, 0, stream>>>(cb, W1, b1, gi, N, 128, 256, 0);
  bn_stats(gi, N, 256, g1, be1, ps, pss, coef, stream);
  k_bn_apply<<<ew2, blk, 0, stream>>>(gi, coef, gh, nullptr, NH, 255, 256, 2);
  k_matvec<<<(N * 64 + 255) / 256, blk, 0, stream>>>(gh, W2, b2, (float*)d_out, N);
}

// Round 3
// 1609.722 us; speedup vs baseline: 3.4914x; 1.1416x over previous
//
#include <hip/hip_runtime.h>
#include <cmath>

#define EPSBN 1e-5f

typedef __attribute__((ext_vector_type(8))) short short8v;
typedef __attribute__((ext_vector_type(4))) short short4v;
typedef __attribute__((ext_vector_type(4))) float f32x4;

__device__ inline unsigned short f2b(float x) {
  union { float f; unsigned int u; } v; v.f = x;
  unsigned int b = v.u;
  return (unsigned short)((b + 0x7FFFu + ((b >> 16) & 1u)) >> 16);
}

// ---------------- graph preprocessing ----------------
__global__ __launch_bounds__(256) void k_count_deg(const int* __restrict__ dst, int* __restrict__ deg, int E) {
  int i = blockIdx.x * 256 + threadIdx.x;
  if (i < E) atomicAdd(&deg[dst[i]], 1);
}

__global__ __launch_bounds__(256) void k_make_dis(const int* __restrict__ deg, float* __restrict__ dis, int N) {
  int i = blockIdx.x * 256 + threadIdx.x;
  if (i < N) dis[i] = rsqrtf((float)(deg[i] + 1));  // +1 self-loop
}

__global__ __launch_bounds__(1024) void k_scan(const int* __restrict__ deg, int* __restrict__ rowptr,
                                               int* __restrict__ cursor, int N) {
  __shared__ int sums[1024];
  int t = threadIdx.x;
  int chunk = (N + 1023) / 1024;
  int beg = min(t * chunk, N), end = min(beg + chunk, N);
  int s = 0;
  for (int i = beg; i < end; ++i) s += deg[i];
  sums[t] = s;
  __syncthreads();
  for (int off = 1; off < 1024; off <<= 1) {
    int v = (t >= off) ? sums[t - off] : 0;
    __syncthreads();
    sums[t] += v;
    __syncthreads();
  }
  int run = (t == 0) ? 0 : sums[t - 1];
  for (int i = beg; i < end; ++i) {
    rowptr[i] = run;
    cursor[i] = run;
    run += deg[i];
  }
  if (t == 1023) rowptr[N] = run;
}

__global__ __launch_bounds__(256) void k_csr_fill(const int* __restrict__ src, const int* __restrict__ dst,
                                                  const float* __restrict__ dis, int* __restrict__ cursor,
                                                  int* __restrict__ csr_src, float* __restrict__ csr_nrm, int E) {
  int e = blockIdx.x * 256 + threadIdx.x;
  if (e >= E) return;
  int s = src[e], d = dst[e];
  int pos = atomicAdd(&cursor[d], 1);
  csr_src[pos] = s;
  csr_nrm[pos] = dis[s] * dis[d];
}

// ---------------- weight prep ----------------
__global__ __launch_bounds__(256) void k_conv_bf16(const float* __restrict__ W, unsigned short* __restrict__ BT, int n) {
  int i = blockIdx.x * 256 + threadIdx.x;
  if (i < n) BT[i] = f2b(W[i]);
}

// W[R][C] -> BT[C][R] (bf16)
__global__ __launch_bounds__(256) void k_trans_bf16(const float* __restrict__ W, unsigned short* __restrict__ BT, int R, int C) {
  int i = blockIdx.x * 256 + threadIdx.x;
  if (i < R * C) { int r = i / C, c = i - r * C; BT[(size_t)c * R + r] = f2b(W[i]); }
}

__global__ void k_fbias(const float* __restrict__ b_ih, float* __restrict__ fb) {
  int i = threadIdx.x;  // 512
  fb[i] = (i < 128) ? 0.f : b_ih[i - 128];
}

// ---------------- bf16 MFMA matmul ----------------
// C[N, M] = A[N,128] @ BT^T  where BT is [M][128] bf16 (row m holds B[:,m]).
// Block tile 128x128, K=128 single stage, 4 waves (2x2 of 64x64), 256 thr.
// LDS XOR-swizzle: byte ^= (row&7)<<4  -> conflict-free-ish b64 frag reads.
template<int ABF>
__global__ __launch_bounds__(256) void k_mmx(const void* __restrict__ Ap, const unsigned short* __restrict__ BT,
                                             const float* __restrict__ bias, float* __restrict__ C,
                                             int N, int ldA, int ldC, int relu)
{
  __shared__ unsigned short As[128 * 128];
  __shared__ unsigned short Bs[128 * 128];
  char* Asb = (char*)As;
  char* Bsb = (char*)Bs;
  int tid = threadIdx.x;
  int brow = blockIdx.y * 128, bcol = blockIdx.x * 128;

  // stage A (128 rows x 128 k, bf16) -- 8 passes of 256 threads x 16B
#pragma unroll
  for (int p = 0; p < 8; ++p) {
    int idx = p * 256 + tid;
    int r = idx >> 4, ch = idx & 15;
    int arow = brow + r;
    short8v v = {0, 0, 0, 0, 0, 0, 0, 0};
    if (ABF) {
      if (arow < N) v = *(const short8v*)((const unsigned short*)Ap + (size_t)arow * ldA + ch * 8);
    } else {
      if (arow < N) {
        const float* a = (const float*)Ap + (size_t)arow * ldA + ch * 8;
        f32x4 x0 = *(const f32x4*)a;
        f32x4 x1 = *(const f32x4*)(a + 4);
        v[0] = (short)f2b(x0[0]); v[1] = (short)f2b(x0[1]);
        v[2] = (short)f2b(x0[2]); v[3] = (short)f2b(x0[3]);
        v[4] = (short)f2b(x1[0]); v[5] = (short)f2b(x1[1]);
        v[6] = (short)f2b(x1[2]); v[7] = (short)f2b(x1[3]);
      }
    }
    *(short8v*)(Asb + r * 256 + ((ch * 16) ^ ((r & 7) << 4))) = v;
  }
  // stage B: rows bcol..bcol+127 of BT (M always a multiple of 128)
#pragma unroll
  for (int p = 0; p < 8; ++p) {
    int idx = p * 256 + tid;
    int r = idx >> 4, ch = idx & 15;
    short8v v = *(const short8v*)(BT + (size_t)(bcol + r) * 128 + ch * 8);
    *(short8v*)(Bsb + r * 256 + ((ch * 16) ^ ((r & 7) << 4))) = v;
  }
  __syncthreads();

  int w = tid >> 6, l = tid & 63;
  int wm = (w >> 1) * 64, wn = (w & 1) * 64;
  int lg = l >> 4, lr = l & 15;
  f32x4 acc[4][4] = {};

#pragma unroll
  for (int ks = 0; ks < 4; ++ks) {
    int kb = ks * 64 + lg * 8;   // byte offset of this lane-group's first k-half
    short8v a[4], b[4];
#pragma unroll
    for (int mt = 0; mt < 4; ++mt) {
      int r = wm + mt * 16 + lr;
      short4v lo = *(const short4v*)(Asb + r * 256 + (kb ^ ((r & 7) << 4)));
      short4v hi = *(const short4v*)(Asb + r * 256 + ((kb + 32) ^ ((r & 7) << 4)));
      a[mt] = __builtin_shufflevector(lo, hi, 0, 1, 2, 3, 4, 5, 6, 7);
    }
#pragma unroll
    for (int nt = 0; nt < 4; ++nt) {
      int r = wn + nt * 16 + lr;
      short4v lo = *(const short4v*)(Bsb + r * 256 + (kb ^ ((r & 7) << 4)));
      short4v hi = *(const short4v*)(Bsb + r * 256 + ((kb + 32) ^ ((r & 7) << 4)));
      b[nt] = __builtin_shufflevector(lo, hi, 0, 1, 2, 3, 4, 5, 6, 7);
    }
#pragma unroll
    for (int mt = 0; mt < 4; ++mt)
#pragma unroll
      for (int nt = 0; nt < 4; ++nt)
        acc[mt][nt] = __builtin_amdgcn_mfma_f32_16x16x32_bf16(a[mt], b[nt], acc[mt][nt], 0, 0, 0);
  }

  // epilogue: C/D layout col=lane&15, row=(lane>>4)*4+reg  [verified m89]
#pragma unroll
  for (int mt = 0; mt < 4; ++mt) {
#pragma unroll
    for (int nt = 0; nt < 4; ++nt) {
      int col = bcol + wn + nt * 16 + lr;
      float bv = bias ? bias[col] : 0.f;
#pragma unroll
      for (int r4 = 0; r4 < 4; ++r4) {
        int row = brow + wm + mt * 16 + lg * 4 + r4;
        if (row < N) {
          float v = acc[mt][nt][r4] + bv;
          if (relu) v = fmaxf(v, 0.f);
          C[(size_t)row * ldC + col] = v;
        }
      }
    }
  }
}

// ---------------- BatchNorm ----------------
__global__ void k_bn_partial(const float* __restrict__ x, int ldx, int N, int D,
                             float* __restrict__ ps, float* __restrict__ pss) {
  int c = threadIdx.x;  // blockDim.x == D
  float s = 0.f, ss = 0.f;
  for (int r = blockIdx.x; r < N; r += gridDim.x) {
    float v = x[(size_t)r * ldx + c];
    s += v; ss += v * v;
  }
  ps[(size_t)blockIdx.x * D + c] = s;
  pss[(size_t)blockIdx.x * D + c] = ss;
}

__global__ void k_bn_finalize(const float* __restrict__ ps, const float* __restrict__ pss,
                              int NB, int D, float invN,
                              const float* __restrict__ gamma, const float* __restrict__ beta,
                              float* __restrict__ coef) {
  int c = threadIdx.x;
  float s = 0.f, ss = 0.f;
  for (int b = 0; b < NB; ++b) { s += ps[(size_t)b * D + c]; ss += pss[(size_t)b * D + c]; }
  float mean = s * invN;
  float var = ss * invN - mean * mean;
  float a = gamma[c] * rsqrtf(var + EPSBN);
  coef[c] = a;
  coef[D + c] = beta[c] - mean * a;
}

// mode: 0 plain; 1 mx=max(mx,v); 2 relu; 3 mx=v. Writes yf (f32) and/or yb (bf16).
__global__ __launch_bounds__(256) void k_bn_apply(const float* __restrict__ x, int ldx, const float* __restrict__ coef,
                                                  float* __restrict__ yf, unsigned short* __restrict__ yb,
                                                  float* __restrict__ mx,
                                                  int total, int Dmask, int shift, int D, int mode) {
  int i = blockIdx.x * 256 + threadIdx.x;
  if (i >= total) return;
  int f = i & Dmask;
  int n = i >> shift;
  float v = x[(size_t)n * ldx + f] * coef[f] + coef[D + f];
  if (mode == 2) v = fmaxf(v, 0.f);
  if (yf) yf[i] = v;
  if (yb) yb[i] = f2b(v);
  if (mode == 1) mx[i] = fmaxf(mx[i], v);
  else if (mode == 3) mx[i] = v;
}

// ---------------- GCN gather (CSR) ----------------
__global__ __launch_bounds__(256) void k_gcn_gather(const int* __restrict__ rowptr, const int* __restrict__ csr_src,
                                                    const float* __restrict__ csr_nrm, const float* __restrict__ dis,
                                                    const float* __restrict__ hp, int ldh,
                                                    const float* __restrict__ bg,
                                                    float* __restrict__ c, unsigned short* __restrict__ cbf, int N) {
  int t = blockIdx.x * 256 + threadIdx.x;
  int g = t >> 5, lane = t & 31;
  if (g >= N) return;
  int off = lane << 2;
  float dd = dis[g];
  float w0 = dd * dd;
  float4 acc = *(const float4*)(bg + off);
  float4 hv = *(const float4*)(hp + (size_t)g * ldh + off);
  acc.x += w0 * hv.x; acc.y += w0 * hv.y; acc.z += w0 * hv.z; acc.w += w0 * hv.w;
  int beg = rowptr[g], end = rowptr[g + 1];
  int j = beg;
  for (; j + 1 < end; j += 2) {
    int s0 = csr_src[j], s1 = csr_src[j + 1];
    float n0 = csr_nrm[j], n1 = csr_nrm[j + 1];
    float4 v0 = *(const float4*)(hp + (size_t)s0 * ldh + off);
    float4 v1 = *(const float4*)(hp + (size_t)s1 * ldh + off);
    acc.x += n0 * v0.x + n1 * v1.x;
    acc.y += n0 * v0.y + n1 * v1.y;
    acc.z += n0 * v0.z + n1 * v1.z;
    acc.w += n0 * v0.w + n1 * v1.w;
  }
  if (j < end) {
    int s0 = csr_src[j];
    float n0 = csr_nrm[j];
    float4 v0 = *(const float4*)(hp + (size_t)s0 * ldh + off);
    acc.x += n0 * v0.x; acc.y += n0 * v0.y; acc.z += n0 * v0.z; acc.w += n0 * v0.w;
  }
  *(float4*)(c + ((size_t)g << 7) + off) = acc;
  short4v b;
  b[0] = (short)f2b(acc.x); b[1] = (short)f2b(acc.y);
  b[2] = (short)f2b(acc.z); b[3] = (short)f2b(acc.w);
  *(short4v*)(cbf + ((size_t)g << 7) + off) = b;
}

// ---------------- GRU gates ----------------
// gi = fused+128 (ld 512), gh (ld 384), c=cb (ld 128); out -> fused cols 0..127 (ld 512)
__global__ __launch_bounds__(256) void k_gru_gates(const float* __restrict__ gi, const float* __restrict__ gh,
                                                   const float* __restrict__ c, float* __restrict__ out, int total) {
  int i = blockIdx.x * 256 + threadIdx.x;
  if (i >= total) return;
  int n = i >> 7, f = i & 127;
  size_t bi = (size_t)n * 512 + f;
  size_t bh = (size_t)n * 384 + f;
  float ir = gi[bi], iz = gi[bi + 128], in_ = gi[bi + 256];
  float hr = gh[bh], hz = gh[bh + 128], hn_ = gh[bh + 256];
  float cv = c[i];
  float r = 1.f / (1.f + expf(-(ir + hr)));
  float z = 1.f / (1.f + expf(-(iz + hz)));
  float nn = tanhf(in_ + r * hn_);
  out[(size_t)n * 512 + f] = (1.f - z) * nn + z * cv;
}

// ---------------- final matvec: out = y2 @ W2 + b2 ----------------
__global__ __launch_bounds__(256) void k_matvec(const float* __restrict__ y, const float* __restrict__ W2,
                                                const float* __restrict__ b2, float* __restrict__ out, int N) {
  int t = blockIdx.x * 256 + threadIdx.x;
  int row = t >> 6, lane = t & 63;
  if (row >= N) return;
  const float* yr = y + (size_t)row * 256;
  float s = 0.f;
#pragma unroll
  for (int k = 0; k < 4; ++k) s += yr[lane + 64 * k] * W2[lane + 64 * k];
#pragma unroll
  for (int off = 32; off > 0; off >>= 1) s += __shfl_down(s, off);
  if (lane == 0) out[row] = s + b2[0];
}

// ---------------- host orchestration ----------------
static void bn_stats(const float* x, int ldx, int N, int D, const float* gamma, const float* beta,
                     float* ps, float* pss, float* coef, hipStream_t stream) {
  const int NB = 256;
  k_bn_partial<<<NB, D, 0, stream>>>(x, ldx, N, D, ps, pss);
  k_bn_finalize<<<1, D, 0, stream>>>(ps, pss, NB, D, 1.0f / (float)N, gamma, beta, coef);
}

extern "C" void kernel_launch(void* const* d_in, const int* in_sizes, int n_in,
                              void* d_out, int out_size, void* d_ws, size_t ws_size,
                              hipStream_t stream) {
  const float* x    = (const float*)d_in[0];
  const int*   ei   = (const int*)d_in[1];
  const float* W_in = (const float*)d_in[2];
  const float* b_in = (const float*)d_in[3];
  const float* g0   = (const float*)d_in[4];
  const float* be0  = (const float*)d_in[5];
  const float* W_g  = (const float*)d_in[6];
  const float* b_g  = (const float*)d_in[7];
  const float* W_ih = (const float*)d_in[8];
  const float* W_hh = (const float*)d_in[9];
  const float* b_ih = (const float*)d_in[10];
  const float* b_hh = (const float*)d_in[11];
  const float* g_c  = (const float*)d_in[12];
  const float* be_c = (const float*)d_in[13];
  const float* g_o  = (const float*)d_in[14];
  const float* be_o = (const float*)d_in[15];
  const float* W1   = (const float*)d_in[16];
  const float* b1   = (const float*)d_in[17];
  const float* g1   = (const float*)d_in[18];
  const float* be1  = (const float*)d_in[19];
  const float* W2   = (const float*)d_in[20];
  const float* b2   = (const float*)d_in[21];

  const int N = in_sizes[0] / 128;   // 30000
  const int E = in_sizes[1] / 2;     // 480000
  const int ND = N * 128;
  const int NH = N * 256;

  float* p     = (float*)d_ws;
  float* fused = p; p += (size_t)N * 512;   // [N][512]: cols 0..127 hp/gru-out, 128..511 gi
  float* gh    = p; p += (size_t)N * 384;
  float* cb    = p; p += ND;
  float* mx    = p; p += ND;
  float* dis   = p; p += ((N + 255) & ~255);
  float* ps    = p; p += 256 * 256;
  float* pss   = p; p += 256 * 256;
  float* coef  = p; p += 1024;
  float* fbias = p; p += 512;
  float* csr_nrm = p; p += E;
  int*   degi    = (int*)p; p += ((N + 255) & ~255);
  int*   rowptr  = (int*)p; p += ((N + 1 + 255) & ~255);
  int*   cursor  = (int*)p; p += ((N + 255) & ~255);
  int*   csr_src = (int*)p; p += E;
  unsigned short* h_bf    = (unsigned short*)p;      // [N][128]
  unsigned short* cb_bf   = h_bf + (size_t)ND;
  unsigned short* fusedBT = cb_bf + (size_t)ND;      // [512][128]
  unsigned short* BThh    = fusedBT + 512 * 128;     // [384][128]
  unsigned short* BTin    = BThh + 384 * 128;        // [128][128]
  unsigned short* BT1     = BTin + 128 * 128;        // [256][128]

  dim3 blk(256);
  int ew  = (ND + 255) / 256;
  int ew2 = (NH + 255) / 256;
  int rb  = (N + 127) / 128;

  // ---- preprocessing (once per launch) ----
  hipMemsetAsync(degi, 0, (size_t)N * sizeof(int), stream);
  k_count_deg<<<(E + 255) / 256, blk, 0, stream>>>(ei + E, degi, E);
  k_make_dis<<<(N + 255) / 256, blk, 0, stream>>>(degi, dis, N);
  k_scan<<<1, 1024, 0, stream>>>(degi, rowptr, cursor, N);
  k_csr_fill<<<(E + 255) / 256, blk, 0, stream>>>(ei, ei + E, dis, cursor, csr_src, csr_nrm, E);
  // weights -> [M][K] bf16
  k_trans_bf16<<<(128 * 128 + 255) / 256, blk, 0, stream>>>(W_g, fusedBT, 128, 128);
  k_conv_bf16<<<(384 * 128 + 255) / 256, blk, 0, stream>>>(W_ih, fusedBT + 128 * 128, 384 * 128);
  k_conv_bf16<<<(384 * 128 + 255) / 256, blk, 0, stream>>>(W_hh, BThh, 384 * 128);
  k_trans_bf16<<<(128 * 128 + 255) / 256, blk, 0, stream>>>(W_in, BTin, 128, 128);
  k_trans_bf16<<<(128 * 256 + 255) / 256, blk, 0, stream>>>(W1, BT1, 128, 256);
  k_fbias<<<1, 512, 0, stream>>>(b_ih, fbias);

  // ---- input layer: fused[:,0:128] = relu(x @ W_in + b_in); BN -> h_bf, mx ----
  k_mmx<0><<<dim3(1, rb), blk, 0, stream>>>(x, BTin, b_in, fused, N, 128, 512, 1);
  bn_stats(fused, 512, N, 128, g0, be0, ps, pss, coef, stream);
  k_bn_apply<<<ew, blk, 0, stream>>>(fused, 512, coef, nullptr, h_bf, mx, ND, 127, 7, 128, 3);

  for (int it = 0; it < 5; ++it) {
    // fused GEMM: [hp | gi] = h @ [W_g | W_ih^T]
    k_mmx<1><<<dim3(4, rb), blk, 0, stream>>>(h_bf, fusedBT, fbias, fused, N, 128, 512, 0);
    // GCN aggregate (reads fused cols 0..127)
    k_gcn_gather<<<(N * 32 + 255) / 256, blk, 0, stream>>>(rowptr, csr_src, csr_nrm, dis, fused, 512, b_g, cb, cb_bf, N);
    // gh = cb @ W_hh^T
    k_mmx<1><<<dim3(3, rb), blk, 0, stream>>>(cb_bf, BThh, b_hh, gh, N, 128, 384, 0);
    // GRU gates -> fused cols 0..127
    k_gru_gates<<<ew, blk, 0, stream>>>(fused + 128, gh, cb, fused, ND);
    // BN + running max -> h_bf, mx
    bn_stats(fused, 512, N, 128, g_c, be_c, ps, pss, coef, stream);
    k_bn_apply<<<ew, blk, 0, stream>>>(fused, 512, coef, nullptr, h_bf, mx, ND, 127, 7, 128, 1);
  }

  // ---- output BN -> encoder ----
  bn_stats(mx, 128, N, 128, g_o, be_o, ps, pss, coef, stream);
  k_bn_apply<<<ew, blk, 0, stream>>>(mx, 128, coef, nullptr, h_bf, nullptr, ND, 127, 7, 128, 0);
  k_mmx<1><<<dim3(2, rb), blk, 0, stream>>>(h_bf, BT1, b1, fused, N, 128, 256, 0);
  bn_stats(fused, 256, N, 256, g1, be1, ps, pss, coef, stream);
  k_bn_apply<<<ew2, blk, 0, stream>>>(fused, 256, coef, gh, nullptr, nullptr, NH, 255, 8, 256, 2);
  k_matvec<<<(N * 64 + 255) / 256, blk, 0, stream>>>(gh, W2, b2, (float*)d_out, N);
}

// Round 4
// 869.898 us; speedup vs baseline: 6.4607x; 1.8505x over previous
//
#include <hip/hip_runtime.h>
#include <cmath>

#define EPSBN 1e-5f

typedef __attribute__((ext_vector_type(8))) short short8v;
typedef __attribute__((ext_vector_type(4))) short short4v;
typedef __attribute__((ext_vector_type(4))) float f32x4;

__device__ inline unsigned short f2b(float x) {
  union { float f; unsigned int u; } v; v.f = x;
  unsigned int b = v.u;
  return (unsigned short)((b + 0x7FFFu + ((b >> 16) & 1u)) >> 16);
}

// ---------------- graph preprocessing ----------------
__global__ __launch_bounds__(256) void k_count_deg(const int* __restrict__ dst, int* __restrict__ deg, int E) {
  int i = blockIdx.x * 256 + threadIdx.x;
  if (i < E) atomicAdd(&deg[dst[i]], 1);
}

__global__ __launch_bounds__(256) void k_make_dis(const int* __restrict__ deg, float* __restrict__ dis, int N) {
  int i = blockIdx.x * 256 + threadIdx.x;
  if (i < N) dis[i] = rsqrtf((float)(deg[i] + 1));  // +1 self-loop
}

// parallel exclusive scan, phase 1: per-block local exclusive scan + block sums
__global__ __launch_bounds__(256) void k_scan_p1(const int* __restrict__ deg, int* __restrict__ rowptr,
                                                 int* __restrict__ bsum, int N) {
  __shared__ int sd[256];
  int t = threadIdx.x;
  int i = blockIdx.x * 256 + t;
  int v = (i < N) ? deg[i] : 0;
  sd[t] = v;
  __syncthreads();
  for (int off = 1; off < 256; off <<= 1) {
    int u = (t >= off) ? sd[t - off] : 0;
    __syncthreads();
    sd[t] += u;
    __syncthreads();
  }
  if (i < N) rowptr[i] = sd[t] - v;   // local exclusive
  if (t == 255) bsum[blockIdx.x] = sd[255];
}

// phase 2: exclusive scan of block sums (NBLK <= 256)
__global__ void k_scan_p2(int* __restrict__ bsum, int NBLK) {
  __shared__ int sd[256];
  int t = threadIdx.x;
  int v = (t < NBLK) ? bsum[t] : 0;
  sd[t] = v;
  __syncthreads();
  for (int off = 1; off < 256; off <<= 1) {
    int u = (t >= off) ? sd[t - off] : 0;
    __syncthreads();
    sd[t] += u;
    __syncthreads();
  }
  if (t < NBLK) bsum[t] = sd[t] - v;
}

// phase 3: add block offsets, fill cursor, write rowptr[N]=E
__global__ __launch_bounds__(256) void k_scan_p3(int* __restrict__ rowptr, int* __restrict__ cursor,
                                                 const int* __restrict__ bsum, int N, int E) {
  int i = blockIdx.x * 256 + threadIdx.x;
  if (i < N) {
    int v = rowptr[i] + bsum[blockIdx.x];
    rowptr[i] = v;
    cursor[i] = v;
  } else if (i == N) {
    rowptr[N] = E;
  }
}

__global__ __launch_bounds__(256) void k_csr_fill(const int* __restrict__ src, const int* __restrict__ dst,
                                                  const float* __restrict__ dis, int* __restrict__ cursor,
                                                  int* __restrict__ csr_src, float* __restrict__ csr_nrm, int E) {
  int e = blockIdx.x * 256 + threadIdx.x;
  if (e >= E) return;
  int s = src[e], d = dst[e];
  int pos = atomicAdd(&cursor[d], 1);
  csr_src[pos] = s;
  csr_nrm[pos] = dis[s] * dis[d];
}

// ---------------- weight prep ----------------
__global__ __launch_bounds__(256) void k_conv_bf16(const float* __restrict__ W, unsigned short* __restrict__ BT, int n) {
  int i = blockIdx.x * 256 + threadIdx.x;
  if (i < n) BT[i] = f2b(W[i]);
}

__global__ __launch_bounds__(256) void k_trans_bf16(const float* __restrict__ W, unsigned short* __restrict__ BT, int R, int C) {
  int i = blockIdx.x * 256 + threadIdx.x;
  if (i < R * C) { int r = i / C, c = i - r * C; BT[(size_t)c * R + r] = f2b(W[i]); }
}

__global__ void k_fbias(const float* __restrict__ b_ih, float* __restrict__ fb) {
  int i = threadIdx.x;  // 512
  fb[i] = (i < 128) ? 0.f : b_ih[i - 128];
}

// ---------------- bf16 MFMA matmul ----------------
// C[N, M] = A[N,128] @ BT^T, BT is [M][128] bf16. Block tile 128x128, K=128,
// 4 waves (2x2 of 64x64). LDS XOR-swizzle byte ^= (row&7)<<4.
// STATS: atomically accumulate column sums/sumsq of the stored value.
template<int ABF, int STATS>
__global__ __launch_bounds__(256) void k_mmx(const void* __restrict__ Ap, const unsigned short* __restrict__ BT,
                                             const float* __restrict__ bias, float* __restrict__ C,
                                             float* __restrict__ psum, float* __restrict__ psqs,
                                             int N, int ldA, int ldC, int relu)
{
  __shared__ unsigned short As[128 * 128];
  __shared__ unsigned short Bs[128 * 128];
  char* Asb = (char*)As;
  char* Bsb = (char*)Bs;
  int tid = threadIdx.x;
  int brow = blockIdx.y * 128, bcol = blockIdx.x * 128;

#pragma unroll
  for (int p = 0; p < 8; ++p) {
    int idx = p * 256 + tid;
    int r = idx >> 4, ch = idx & 15;
    int arow = brow + r;
    short8v v = {0, 0, 0, 0, 0, 0, 0, 0};
    if (ABF) {
      if (arow < N) v = *(const short8v*)((const unsigned short*)Ap + (size_t)arow * ldA + ch * 8);
    } else {
      if (arow < N) {
        const float* a = (const float*)Ap + (size_t)arow * ldA + ch * 8;
        f32x4 x0 = *(const f32x4*)a;
        f32x4 x1 = *(const f32x4*)(a + 4);
        v[0] = (short)f2b(x0[0]); v[1] = (short)f2b(x0[1]);
        v[2] = (short)f2b(x0[2]); v[3] = (short)f2b(x0[3]);
        v[4] = (short)f2b(x1[0]); v[5] = (short)f2b(x1[1]);
        v[6] = (short)f2b(x1[2]); v[7] = (short)f2b(x1[3]);
      }
    }
    *(short8v*)(Asb + r * 256 + ((ch * 16) ^ ((r & 7) << 4))) = v;
  }
#pragma unroll
  for (int p = 0; p < 8; ++p) {
    int idx = p * 256 + tid;
    int r = idx >> 4, ch = idx & 15;
    short8v v = *(const short8v*)(BT + (size_t)(bcol + r) * 128 + ch * 8);
    *(short8v*)(Bsb + r * 256 + ((ch * 16) ^ ((r & 7) << 4))) = v;
  }
  __syncthreads();

  int w = tid >> 6, l = tid & 63;
  int wm = (w >> 1) * 64, wn = (w & 1) * 64;
  int lg = l >> 4, lr = l & 15;
  f32x4 acc[4][4] = {};

#pragma unroll
  for (int ks = 0; ks < 4; ++ks) {
    int kb = ks * 64 + lg * 8;
    short8v a[4], b[4];
#pragma unroll
    for (int mt = 0; mt < 4; ++mt) {
      int r = wm + mt * 16 + lr;
      short4v lo = *(const short4v*)(Asb + r * 256 + (kb ^ ((r & 7) << 4)));
      short4v hi = *(const short4v*)(Asb + r * 256 + ((kb + 32) ^ ((r & 7) << 4)));
      a[mt] = __builtin_shufflevector(lo, hi, 0, 1, 2, 3, 4, 5, 6, 7);
    }
#pragma unroll
    for (int nt = 0; nt < 4; ++nt) {
      int r = wn + nt * 16 + lr;
      short4v lo = *(const short4v*)(Bsb + r * 256 + (kb ^ ((r & 7) << 4)));
      short4v hi = *(const short4v*)(Bsb + r * 256 + ((kb + 32) ^ ((r & 7) << 4)));
      b[nt] = __builtin_shufflevector(lo, hi, 0, 1, 2, 3, 4, 5, 6, 7);
    }
#pragma unroll
    for (int mt = 0; mt < 4; ++mt)
#pragma unroll
      for (int nt = 0; nt < 4; ++nt)
        acc[mt][nt] = __builtin_amdgcn_mfma_f32_16x16x32_bf16(a[mt], b[nt], acc[mt][nt], 0, 0, 0);
  }

  float sc[4] = {0.f, 0.f, 0.f, 0.f}, scc[4] = {0.f, 0.f, 0.f, 0.f};
#pragma unroll
  for (int mt = 0; mt < 4; ++mt) {
#pragma unroll
    for (int nt = 0; nt < 4; ++nt) {
      int col = bcol + wn + nt * 16 + lr;
      float bv = bias ? bias[col] : 0.f;
#pragma unroll
      for (int r4 = 0; r4 < 4; ++r4) {
        int row = brow + wm + mt * 16 + lg * 4 + r4;
        if (row < N) {
          float v = acc[mt][nt][r4] + bv;
          if (relu) v = fmaxf(v, 0.f);
          C[(size_t)row * ldC + col] = v;
          if (STATS) { sc[nt] += v; scc[nt] += v * v; }
        }
      }
    }
  }
  if (STATS) {
#pragma unroll
    for (int nt = 0; nt < 4; ++nt) {
      float s = sc[nt], ss = scc[nt];
      s += __shfl_xor(s, 16); s += __shfl_xor(s, 32);
      ss += __shfl_xor(ss, 16); ss += __shfl_xor(ss, 32);
      if (lg == 0) {
        int col = bcol + wn + nt * 16 + lr;
        atomicAdd(&psum[col], s);
        atomicAdd(&psqs[col], ss);
      }
    }
  }
}

// ---------------- GRU gates (column-parallel, fused BN stats) ----------------
// blockDim 512 = 128 cols x 4 row-groups; 128 rows per block.
__global__ __launch_bounds__(512) void k_gru(const float* __restrict__ fused, const float* __restrict__ gh,
                                             const float* __restrict__ cb, float* __restrict__ out,
                                             float* __restrict__ psum, float* __restrict__ psqs, int N) {
  int tx = threadIdx.x & 127, ty = threadIdx.x >> 7;
  int n0 = blockIdx.x * 128;
  float s = 0.f, ss = 0.f;
  for (int r = ty; r < 128; r += 4) {
    int n = n0 + r;
    if (n >= N) break;
    size_t bi = (size_t)n * 512 + tx;
    size_t bh = (size_t)n * 384 + tx;
    float ir = fused[bi + 128], iz = fused[bi + 256], in_ = fused[bi + 384];
    float hr = gh[bh], hz = gh[bh + 128], hn_ = gh[bh + 256];
    float cv = cb[(size_t)n * 128 + tx];
    float rr = 1.f / (1.f + expf(-(ir + hr)));
    float z  = 1.f / (1.f + expf(-(iz + hz)));
    float nn = tanhf(in_ + rr * hn_);
    float v = (1.f - z) * nn + z * cv;
    out[(size_t)n * 512 + tx] = v;
    s += v; ss += v * v;
  }
  __shared__ float sd[2][4][128];
  sd[0][ty][tx] = s; sd[1][ty][tx] = ss;
  __syncthreads();
  if (ty == 0) {
    s  = sd[0][0][tx] + sd[0][1][tx] + sd[0][2][tx] + sd[0][3][tx];
    ss = sd[1][0][tx] + sd[1][1][tx] + sd[1][2][tx] + sd[1][3][tx];
    atomicAdd(&psum[tx], s);
    atomicAdd(&psqs[tx], ss);
  }
}

// ---------------- BN apply (coef computed in-block from summed stats) ----------------
// MODE: 0 plain; 1 w=max(mx,v)->mx; 2 relu; 3 mx=v. STATS: accumulate stats of w.
// blockDim 512 = D cols x (512/D) row-groups; R rows per block (32 per thread).
template<int MODE, int STATS>
__global__ __launch_bounds__(512) void k_bn_apply(const float* __restrict__ x, int ldx,
                                                  const float* __restrict__ psum, const float* __restrict__ psqs,
                                                  const float* __restrict__ gamma, const float* __restrict__ beta,
                                                  float invN,
                                                  unsigned short* __restrict__ yb, float* __restrict__ yf,
                                                  float* __restrict__ mx,
                                                  float* __restrict__ npsum, float* __restrict__ npsqs,
                                                  int N, int D, int R) {
  __shared__ float cA[256], cB[256];
  int t = threadIdx.x;
  if (t < D) {
    float m = psum[t] * invN;
    float var = psqs[t] * invN - m * m;
    float a = gamma[t] * rsqrtf(var + EPSBN);
    cA[t] = a; cB[t] = beta[t] - m * a;
  }
  __syncthreads();
  int TY = 512 / D;
  int tx = t % D, ty = t / D;
  int n0 = blockIdx.x * R;
  float s = 0.f, ss = 0.f;
  for (int r = ty; r < R; r += TY) {
    int n = n0 + r;
    if (n >= N) break;
    float v = x[(size_t)n * ldx + tx] * cA[tx] + cB[tx];
    if (MODE == 2) v = fmaxf(v, 0.f);
    float w = v;
    if (MODE == 1) {
      size_t mi = (size_t)n * D + tx;
      w = fmaxf(mx[mi], v);
      mx[mi] = w;
    } else if (MODE == 3) {
      mx[(size_t)n * D + tx] = v;
    }
    if (yb) yb[(size_t)n * D + tx] = f2b(v);
    if (yf) yf[(size_t)n * D + tx] = v;
    if (STATS) { s += w; ss += w * w; }
  }
  if (STATS) {
    __shared__ float sd[2][4][256];
    sd[0][ty][tx] = s; sd[1][ty][tx] = ss;
    __syncthreads();
    if (ty == 0) {
      for (int q = 1; q < TY; ++q) { s += sd[0][q][tx]; ss += sd[1][q][tx]; }
      atomicAdd(&npsum[tx], s);
      atomicAdd(&npsqs[tx], ss);
    }
  }
}

// ---------------- GCN gather (CSR) ----------------
__global__ __launch_bounds__(256) void k_gcn_gather(const int* __restrict__ rowptr, const int* __restrict__ csr_src,
                                                    const float* __restrict__ csr_nrm, const float* __restrict__ dis,
                                                    const float* __restrict__ hp, int ldh,
                                                    const float* __restrict__ bg,
                                                    float* __restrict__ c, unsigned short* __restrict__ cbf, int N) {
  int t = blockIdx.x * 256 + threadIdx.x;
  int g = t >> 5, lane = t & 31;
  if (g >= N) return;
  int off = lane << 2;
  float dd = dis[g];
  float w0 = dd * dd;
  float4 acc = *(const float4*)(bg + off);
  float4 hv = *(const float4*)(hp + (size_t)g * ldh + off);
  acc.x += w0 * hv.x; acc.y += w0 * hv.y; acc.z += w0 * hv.z; acc.w += w0 * hv.w;
  int beg = rowptr[g], end = rowptr[g + 1];
  int j = beg;
  for (; j + 3 < end; j += 4) {
    int s0 = csr_src[j], s1 = csr_src[j + 1], s2 = csr_src[j + 2], s3 = csr_src[j + 3];
    float n0 = csr_nrm[j], n1 = csr_nrm[j + 1], n2 = csr_nrm[j + 2], n3 = csr_nrm[j + 3];
    float4 v0 = *(const float4*)(hp + (size_t)s0 * ldh + off);
    float4 v1 = *(const float4*)(hp + (size_t)s1 * ldh + off);
    float4 v2 = *(const float4*)(hp + (size_t)s2 * ldh + off);
    float4 v3 = *(const float4*)(hp + (size_t)s3 * ldh + off);
    acc.x += n0 * v0.x + n1 * v1.x + n2 * v2.x + n3 * v3.x;
    acc.y += n0 * v0.y + n1 * v1.y + n2 * v2.y + n3 * v3.y;
    acc.z += n0 * v0.z + n1 * v1.z + n2 * v2.z + n3 * v3.z;
    acc.w += n0 * v0.w + n1 * v1.w + n2 * v2.w + n3 * v3.w;
  }
  for (; j < end; ++j) {
    int s0 = csr_src[j];
    float n0 = csr_nrm[j];
    float4 v0 = *(const float4*)(hp + (size_t)s0 * ldh + off);
    acc.x += n0 * v0.x; acc.y += n0 * v0.y; acc.z += n0 * v0.z; acc.w += n0 * v0.w;
  }
  *(float4*)(c + ((size_t)g << 7) + off) = acc;
  short4v b;
  b[0] = (short)f2b(acc.x); b[1] = (short)f2b(acc.y);
  b[2] = (short)f2b(acc.z); b[3] = (short)f2b(acc.w);
  *(short4v*)(cbf + ((size_t)g << 7) + off) = b;
}

// ---------------- final matvec: out = y2 @ W2 + b2 ----------------
__global__ __launch_bounds__(256) void k_matvec(const float* __restrict__ y, const float* __restrict__ W2,
                                                const float* __restrict__ b2, float* __restrict__ out, int N) {
  int t = blockIdx.x * 256 + threadIdx.x;
  int row = t >> 6, lane = t & 63;
  if (row >= N) return;
  const float* yr = y + (size_t)row * 256;
  float s = 0.f;
#pragma unroll
  for (int k = 0; k < 4; ++k) s += yr[lane + 64 * k] * W2[lane + 64 * k];
#pragma unroll
  for (int off = 32; off > 0; off >>= 1) s += __shfl_down(s, off);
  if (lane == 0) out[row] = s + b2[0];
}

// ---------------- host orchestration ----------------
extern "C" void kernel_launch(void* const* d_in, const int* in_sizes, int n_in,
                              void* d_out, int out_size, void* d_ws, size_t ws_size,
                              hipStream_t stream) {
  const float* x    = (const float*)d_in[0];
  const int*   ei   = (const int*)d_in[1];
  const float* W_in = (const float*)d_in[2];
  const float* b_in = (const float*)d_in[3];
  const float* g0   = (const float*)d_in[4];
  const float* be0  = (const float*)d_in[5];
  const float* W_g  = (const float*)d_in[6];
  const float* b_g  = (const float*)d_in[7];
  const float* W_ih = (const float*)d_in[8];
  const float* W_hh = (const float*)d_in[9];
  const float* b_ih = (const float*)d_in[10];
  const float* b_hh = (const float*)d_in[11];
  const float* g_c  = (const float*)d_in[12];
  const float* be_c = (const float*)d_in[13];
  const float* g_o  = (const float*)d_in[14];
  const float* be_o = (const float*)d_in[15];
  const float* W1   = (const float*)d_in[16];
  const float* b1   = (const float*)d_in[17];
  const float* g1   = (const float*)d_in[18];
  const float* be1  = (const float*)d_in[19];
  const float* W2   = (const float*)d_in[20];
  const float* b2   = (const float*)d_in[21];

  const int N = in_sizes[0] / 128;   // 30000
  const int E = in_sizes[1] / 2;     // 480000
  const int ND = N * 128;
  const float invN = 1.0f / (float)N;

  float* p     = (float*)d_ws;
  float* fused = p; p += (size_t)N * 512;   // [N][512]: cols 0..127 conv/gru-out, 128..511 gi
  float* ghb   = p; p += (size_t)N * 384;
  float* cb    = p; p += ND;
  float* mx    = p; p += ND;
  float* dis   = p; p += ((N + 255) & ~255);
  float* stats = p; p += 8 * 512;           // 8 slots: [psum(256) | psqs(256)]
  float* fbias = p; p += 512;
  float* csr_nrm = p; p += E;
  int*   degi    = (int*)p; p += ((N + 255) & ~255);
  int*   rowptr  = (int*)p; p += ((N + 1 + 255) & ~255);
  int*   cursor  = (int*)p; p += ((N + 255) & ~255);
  int*   bsum    = (int*)p; p += 256;
  int*   csr_src = (int*)p; p += E;
  unsigned short* h_bf    = (unsigned short*)p;      // [N][128]
  unsigned short* cb_bf   = h_bf + (size_t)ND;
  unsigned short* fusedBT = cb_bf + (size_t)ND;      // [512][128]
  unsigned short* BThh    = fusedBT + 512 * 128;     // [384][128]
  unsigned short* BTin    = BThh + 384 * 128;        // [128][128]
  unsigned short* BT1     = BTin + 128 * 128;        // [256][128]

  float* ps0 = stats;              // input BN
  float* psc[5];
  for (int i = 0; i < 5; ++i) psc[i] = stats + 512 * (1 + i);
  float* pso = stats + 512 * 6;    // output (mx) BN
  float* ps1 = stats + 512 * 7;    // encoder BN (D=256)

  dim3 blk(256);
  int rb = (N + 127) / 128;
  int NBLK = (N + 255) / 256;

  // ---- preprocessing ----
  hipMemsetAsync(degi, 0, (size_t)N * sizeof(int), stream);
  hipMemsetAsync(stats, 0, 8 * 512 * sizeof(float), stream);
  k_count_deg<<<(E + 255) / 256, blk, 0, stream>>>(ei + E, degi, E);
  k_make_dis<<<(N + 255) / 256, blk, 0, stream>>>(degi, dis, N);
  k_scan_p1<<<NBLK, blk, 0, stream>>>(degi, rowptr, bsum, N);
  k_scan_p2<<<1, blk, 0, stream>>>(bsum, NBLK);
  k_scan_p3<<<(N + 256) / 256, blk, 0, stream>>>(rowptr, cursor, bsum, N, E);
  k_csr_fill<<<(E + 255) / 256, blk, 0, stream>>>(ei, ei + E, dis, cursor, csr_src, csr_nrm, E);
  k_trans_bf16<<<(128 * 128 + 255) / 256, blk, 0, stream>>>(W_g, fusedBT, 128, 128);
  k_conv_bf16<<<(384 * 128 + 255) / 256, blk, 0, stream>>>(W_ih, fusedBT + 128 * 128, 384 * 128);
  k_conv_bf16<<<(384 * 128 + 255) / 256, blk, 0, stream>>>(W_hh, BThh, 384 * 128);
  k_trans_bf16<<<(128 * 128 + 255) / 256, blk, 0, stream>>>(W_in, BTin, 128, 128);
  k_trans_bf16<<<(128 * 256 + 255) / 256, blk, 0, stream>>>(W1, BT1, 128, 256);
  k_fbias<<<1, 512, 0, stream>>>(b_ih, fbias);

  // ---- input layer: relu(x@W_in+b_in) -> fused[:,0:128], stats -> ps0 ----
  k_mmx<0, 1><<<dim3(1, rb), blk, 0, stream>>>(x, BTin, b_in, fused, ps0, ps0 + 256, N, 128, 512, 1);
  // BN apply: h_bf = bf16(v), mx = v
  k_bn_apply<3, 0><<<(N + 127) / 128, 512, 0, stream>>>(fused, 512, ps0, ps0 + 256, g0, be0, invN,
                                                        h_bf, nullptr, mx, nullptr, nullptr, N, 128, 128);

  for (int it = 0; it < 5; ++it) {
    // fused GEMM: [conv_in | gi] = h @ [W_g | W_ih^T]
    k_mmx<1, 0><<<dim3(4, rb), blk, 0, stream>>>(h_bf, fusedBT, fbias, fused, nullptr, nullptr, N, 128, 512, 0);
    // GCN aggregate
    k_gcn_gather<<<(N * 32 + 255) / 256, blk, 0, stream>>>(rowptr, csr_src, csr_nrm, dis, fused, 512, b_g, cb, cb_bf, N);
    // gh = cb @ W_hh^T
    k_mmx<1, 0><<<dim3(3, rb), blk, 0, stream>>>(cb_bf, BThh, b_hh, ghb, nullptr, nullptr, N, 128, 384, 0);
    // GRU gates -> fused cols 0..127, stats -> psc[it]
    k_gru<<<(N + 127) / 128, 512, 0, stream>>>(fused, ghb, cb, fused, psc[it], psc[it] + 256, N);
    // BN + running max; last iter also accumulates mx stats -> pso
    if (it < 4)
      k_bn_apply<1, 0><<<(N + 127) / 128, 512, 0, stream>>>(fused, 512, psc[it], psc[it] + 256, g_c, be_c, invN,
                                                            h_bf, nullptr, mx, nullptr, nullptr, N, 128, 128);
    else
      k_bn_apply<1, 1><<<(N + 127) / 128, 512, 0, stream>>>(fused, 512, psc[it], psc[it] + 256, g_c, be_c, invN,
                                                            h_bf, nullptr, mx, pso, pso + 256, N, 128, 128);
  }

  // ---- output BN on mx -> h_bf ----
  k_bn_apply<0, 0><<<(N + 127) / 128, 512, 0, stream>>>(mx, 128, pso, pso + 256, g_o, be_o, invN,
                                                        h_bf, nullptr, nullptr, nullptr, nullptr, N, 128, 128);
  // ---- encoder: fused[:,0:256] = h_bf @ W1 + b1, stats -> ps1 ----
  k_mmx<1, 1><<<dim3(2, rb), blk, 0, stream>>>(h_bf, BT1, b1, fused, ps1, ps1 + 256, N, 128, 256, 0);
  // BN + relu -> ghb (f32, ld 256)
  k_bn_apply<2, 0><<<(N + 63) / 64, 512, 0, stream>>>(fused, 256, ps1, ps1 + 256, g1, be1, invN,
                                                      nullptr, ghb, nullptr, nullptr, nullptr, N, 256, 64);
  k_matvec<<<(N * 64 + 255) / 256, blk, 0, stream>>>(ghb, W2, b2, (float*)d_out, N);
}

// Round 5
// 813.295 us; speedup vs baseline: 6.9103x; 1.0696x over previous
//
#include <hip/hip_runtime.h>
#include <cmath>

#define EPSBN 1e-5f

typedef __attribute__((ext_vector_type(8))) short short8v;
typedef __attribute__((ext_vector_type(4))) short short4v;
typedef __attribute__((ext_vector_type(4))) float f32x4;

__device__ inline unsigned short f2b(float x) {
  union { float f; unsigned int u; } v; v.f = x;
  unsigned int b = v.u;
  return (unsigned short)((b + 0x7FFFu + ((b >> 16) & 1u)) >> 16);
}
__device__ inline float b2f(unsigned short x) {
  union { unsigned int u; float f; } v; v.u = ((unsigned int)x) << 16;
  return v.f;
}

// ---------------- graph preprocessing ----------------
__global__ __launch_bounds__(256) void k_count_deg(const int* __restrict__ dst, int* __restrict__ deg, int E) {
  int i = blockIdx.x * 256 + threadIdx.x;
  if (i < E) atomicAdd(&deg[dst[i]], 1);
}

// per-block local exclusive scan + block sums; also dis = rsqrt(deg+1)
__global__ __launch_bounds__(256) void k_scan_p1(const int* __restrict__ deg, int* __restrict__ rowptr,
                                                 int* __restrict__ bsum, float* __restrict__ dis, int N) {
  __shared__ int sd[256];
  int t = threadIdx.x;
  int i = blockIdx.x * 256 + t;
  int v = (i < N) ? deg[i] : 0;
  if (i < N) dis[i] = rsqrtf((float)(v + 1));
  sd[t] = v;
  __syncthreads();
  for (int off = 1; off < 256; off <<= 1) {
    int u = (t >= off) ? sd[t - off] : 0;
    __syncthreads();
    sd[t] += u;
    __syncthreads();
  }
  if (i < N) rowptr[i] = sd[t] - v;
  if (t == 255) bsum[blockIdx.x] = sd[255];
}

__global__ void k_scan_p2(int* __restrict__ bsum, int NBLK) {
  __shared__ int sd[256];
  int t = threadIdx.x;
  int v = (t < NBLK) ? bsum[t] : 0;
  sd[t] = v;
  __syncthreads();
  for (int off = 1; off < 256; off <<= 1) {
    int u = (t >= off) ? sd[t - off] : 0;
    __syncthreads();
    sd[t] += u;
    __syncthreads();
  }
  if (t < NBLK) bsum[t] = sd[t] - v;
}

__global__ __launch_bounds__(256) void k_scan_p3(int* __restrict__ rowptr, int* __restrict__ cursor,
                                                 const int* __restrict__ bsum, int N, int E) {
  int i = blockIdx.x * 256 + threadIdx.x;
  if (i < N) {
    int v = rowptr[i] + bsum[blockIdx.x];
    rowptr[i] = v;
    cursor[i] = v;
  } else if (i == N) {
    rowptr[N] = E;
  }
}

__global__ __launch_bounds__(256) void k_csr_fill(const int* __restrict__ src, const int* __restrict__ dst,
                                                  const float* __restrict__ dis, int* __restrict__ cursor,
                                                  int* __restrict__ csr_src, float* __restrict__ csr_nrm, int E) {
  int e = blockIdx.x * 256 + threadIdx.x;
  if (e >= E) return;
  int s = src[e], d = dst[e];
  int pos = atomicAdd(&cursor[d], 1);
  csr_src[pos] = s;
  csr_nrm[pos] = dis[s] * dis[d];
}

// ---------------- fused weight prep (single kernel) ----------------
// regions: [0,16384) W_g trans; [.,+49152) W_ih copy; [.,+49152) W_hh copy;
// [.,+16384) W_in trans; [.,+32768) W1 trans; [.,+512) fused bias
__global__ __launch_bounds__(256) void k_wprep(const float* __restrict__ W_g, const float* __restrict__ W_ih,
                                               const float* __restrict__ W_hh, const float* __restrict__ W_in,
                                               const float* __restrict__ W1, const float* __restrict__ b_ih,
                                               unsigned short* __restrict__ fusedBT, unsigned short* __restrict__ BThh,
                                               unsigned short* __restrict__ BTin, unsigned short* __restrict__ BT1,
                                               float* __restrict__ fbias) {
  int i = blockIdx.x * 256 + threadIdx.x;
  if (i < 16384) {
    int k = i >> 7, m = i & 127;
    fusedBT[m * 128 + k] = f2b(W_g[i]);
  } else if (i < 16384 + 49152) {
    int j = i - 16384;
    fusedBT[16384 + j] = f2b(W_ih[j]);
  } else if (i < 65536 + 49152) {
    int j = i - 65536;
    BThh[j] = f2b(W_hh[j]);
  } else if (i < 114688 + 16384) {
    int j = i - 114688;
    int k = j >> 7, m = j & 127;
    BTin[m * 128 + k] = f2b(W_in[j]);
  } else if (i < 131072 + 32768) {
    int j = i - 131072;
    int k = j >> 8, m = j & 255;
    BT1[m * 128 + k] = f2b(W1[j]);
  } else if (i < 163840 + 512) {
    int j = i - 163840;
    fbias[j] = (j < 128) ? 0.f : b_ih[j - 128];
  }
}

// ---------------- bf16 MFMA matmul ----------------
// C = A[N,128] @ BT^T, BT is [M][128] bf16. Block tile 128x128, K=128,
// 4 waves (2x2 of 64x64). LDS XOR-swizzle byte ^= (row&7)<<4.
// SPLIT: col-block 0 writes bf16 to Cb[n*128+col]; others write f32 to
//        Cf[n*ldC + col-128]. Otherwise all cols -> f32 Cf[n*ldC+col].
template<int ABF, int STATS, int SPLIT>
__global__ __launch_bounds__(256) void k_mmx(const void* __restrict__ Ap, const unsigned short* __restrict__ BT,
                                             const float* __restrict__ bias,
                                             float* __restrict__ Cf, unsigned short* __restrict__ Cb,
                                             float* __restrict__ psum, float* __restrict__ psqs,
                                             int N, int ldA, int ldC, int relu)
{
  __shared__ unsigned short As[128 * 128];
  __shared__ unsigned short Bs[128 * 128];
  char* Asb = (char*)As;
  char* Bsb = (char*)Bs;
  int tid = threadIdx.x;
  int brow = blockIdx.y * 128, bcol = blockIdx.x * 128;

#pragma unroll
  for (int p = 0; p < 8; ++p) {
    int idx = p * 256 + tid;
    int r = idx >> 4, ch = idx & 15;
    int arow = brow + r;
    short8v v = {0, 0, 0, 0, 0, 0, 0, 0};
    if (ABF) {
      if (arow < N) v = *(const short8v*)((const unsigned short*)Ap + (size_t)arow * ldA + ch * 8);
    } else {
      if (arow < N) {
        const float* a = (const float*)Ap + (size_t)arow * ldA + ch * 8;
        f32x4 x0 = *(const f32x4*)a;
        f32x4 x1 = *(const f32x4*)(a + 4);
        v[0] = (short)f2b(x0[0]); v[1] = (short)f2b(x0[1]);
        v[2] = (short)f2b(x0[2]); v[3] = (short)f2b(x0[3]);
        v[4] = (short)f2b(x1[0]); v[5] = (short)f2b(x1[1]);
        v[6] = (short)f2b(x1[2]); v[7] = (short)f2b(x1[3]);
      }
    }
    *(short8v*)(Asb + r * 256 + ((ch * 16) ^ ((r & 7) << 4))) = v;
  }
#pragma unroll
  for (int p = 0; p < 8; ++p) {
    int idx = p * 256 + tid;
    int r = idx >> 4, ch = idx & 15;
    short8v v = *(const short8v*)(BT + (size_t)(bcol + r) * 128 + ch * 8);
    *(short8v*)(Bsb + r * 256 + ((ch * 16) ^ ((r & 7) << 4))) = v;
  }
  __syncthreads();

  int w = tid >> 6, l = tid & 63;
  int wm = (w >> 1) * 64, wn = (w & 1) * 64;
  int lg = l >> 4, lr = l & 15;
  f32x4 acc[4][4] = {};

#pragma unroll
  for (int ks = 0; ks < 4; ++ks) {
    int kb = ks * 64 + lg * 8;
    short8v a[4], b[4];
#pragma unroll
    for (int mt = 0; mt < 4; ++mt) {
      int r = wm + mt * 16 + lr;
      short4v lo = *(const short4v*)(Asb + r * 256 + (kb ^ ((r & 7) << 4)));
      short4v hi = *(const short4v*)(Asb + r * 256 + ((kb + 32) ^ ((r & 7) << 4)));
      a[mt] = __builtin_shufflevector(lo, hi, 0, 1, 2, 3, 4, 5, 6, 7);
    }
#pragma unroll
    for (int nt = 0; nt < 4; ++nt) {
      int r = wn + nt * 16 + lr;
      short4v lo = *(const short4v*)(Bsb + r * 256 + (kb ^ ((r & 7) << 4)));
      short4v hi = *(const short4v*)(Bsb + r * 256 + ((kb + 32) ^ ((r & 7) << 4)));
      b[nt] = __builtin_shufflevector(lo, hi, 0, 1, 2, 3, 4, 5, 6, 7);
    }
#pragma unroll
    for (int mt = 0; mt < 4; ++mt)
#pragma unroll
      for (int nt = 0; nt < 4; ++nt)
        acc[mt][nt] = __builtin_amdgcn_mfma_f32_16x16x32_bf16(a[mt], b[nt], acc[mt][nt], 0, 0, 0);
  }

  float sc[4] = {0.f, 0.f, 0.f, 0.f}, scc[4] = {0.f, 0.f, 0.f, 0.f};
  bool bfdest = SPLIT && (bcol == 0);
#pragma unroll
  for (int mt = 0; mt < 4; ++mt) {
#pragma unroll
    for (int nt = 0; nt < 4; ++nt) {
      int col = bcol + wn + nt * 16 + lr;
      float bv = bias ? bias[col] : 0.f;
#pragma unroll
      for (int r4 = 0; r4 < 4; ++r4) {
        int row = brow + wm + mt * 16 + lg * 4 + r4;
        if (row < N) {
          float v = acc[mt][nt][r4] + bv;
          if (relu) v = fmaxf(v, 0.f);
          if (bfdest) {
            Cb[(size_t)row * 128 + col] = f2b(v);
          } else {
            int cc = SPLIT ? (col - 128) : col;
            Cf[(size_t)row * ldC + cc] = v;
          }
          if (STATS) { sc[nt] += v; scc[nt] += v * v; }
        }
      }
    }
  }
  if (STATS) {
#pragma unroll
    for (int nt = 0; nt < 4; ++nt) {
      float s = sc[nt], ss = scc[nt];
      s += __shfl_xor(s, 16); s += __shfl_xor(s, 32);
      ss += __shfl_xor(ss, 16); ss += __shfl_xor(ss, 32);
      if (lg == 0) {
        int col = bcol + wn + nt * 16 + lr;
        atomicAdd(&psum[col], s);
        atomicAdd(&psqs[col], ss);
      }
    }
  }
}

// ---------------- GCN gather (CSR, bf16 inputs) ----------------
__global__ __launch_bounds__(256) void k_gcn_gather(const int* __restrict__ rowptr, const int* __restrict__ csr_src,
                                                    const float* __restrict__ csr_nrm, const float* __restrict__ dis,
                                                    const unsigned short* __restrict__ hp,
                                                    const float* __restrict__ bg,
                                                    float* __restrict__ c, unsigned short* __restrict__ cbf, int N) {
  int t = blockIdx.x * 256 + threadIdx.x;
  int g = t >> 5, lane = t & 31;
  if (g >= N) return;
  int off = lane << 2;
  float dd = dis[g];
  float w0 = dd * dd;
  float4 acc = *(const float4*)(bg + off);
  short4v hv = *(const short4v*)(hp + ((size_t)g << 7) + off);
  acc.x += w0 * b2f((unsigned short)hv[0]);
  acc.y += w0 * b2f((unsigned short)hv[1]);
  acc.z += w0 * b2f((unsigned short)hv[2]);
  acc.w += w0 * b2f((unsigned short)hv[3]);
  int beg = rowptr[g], end = rowptr[g + 1];
  int j = beg;
  for (; j + 3 < end; j += 4) {
    int s0 = csr_src[j], s1 = csr_src[j + 1], s2 = csr_src[j + 2], s3 = csr_src[j + 3];
    float n0 = csr_nrm[j], n1 = csr_nrm[j + 1], n2 = csr_nrm[j + 2], n3 = csr_nrm[j + 3];
    short4v v0 = *(const short4v*)(hp + ((size_t)s0 << 7) + off);
    short4v v1 = *(const short4v*)(hp + ((size_t)s1 << 7) + off);
    short4v v2 = *(const short4v*)(hp + ((size_t)s2 << 7) + off);
    short4v v3 = *(const short4v*)(hp + ((size_t)s3 << 7) + off);
    acc.x += n0 * b2f((unsigned short)v0[0]) + n1 * b2f((unsigned short)v1[0]) + n2 * b2f((unsigned short)v2[0]) + n3 * b2f((unsigned short)v3[0]);
    acc.y += n0 * b2f((unsigned short)v0[1]) + n1 * b2f((unsigned short)v1[1]) + n2 * b2f((unsigned short)v2[1]) + n3 * b2f((unsigned short)v3[1]);
    acc.z += n0 * b2f((unsigned short)v0[2]) + n1 * b2f((unsigned short)v1[2]) + n2 * b2f((unsigned short)v2[2]) + n3 * b2f((unsigned short)v3[2]);
    acc.w += n0 * b2f((unsigned short)v0[3]) + n1 * b2f((unsigned short)v1[3]) + n2 * b2f((unsigned short)v2[3]) + n3 * b2f((unsigned short)v3[3]);
  }
  for (; j < end; ++j) {
    int s0 = csr_src[j];
    float n0 = csr_nrm[j];
    short4v v0 = *(const short4v*)(hp + ((size_t)s0 << 7) + off);
    acc.x += n0 * b2f((unsigned short)v0[0]);
    acc.y += n0 * b2f((unsigned short)v0[1]);
    acc.z += n0 * b2f((unsigned short)v0[2]);
    acc.w += n0 * b2f((unsigned short)v0[3]);
  }
  *(float4*)(c + ((size_t)g << 7) + off) = acc;
  short4v b;
  b[0] = (short)f2b(acc.x); b[1] = (short)f2b(acc.y);
  b[2] = (short)f2b(acc.z); b[3] = (short)f2b(acc.w);
  *(short4v*)(cbf + ((size_t)g << 7) + off) = b;
}

// ---------------- GRU gates (column-parallel, fused BN stats) ----------------
// gi from gib (ld 384), gh from ghb (ld 384), cv from cb (ld 128); writes cb in place.
__global__ __launch_bounds__(512) void k_gru(const float* __restrict__ gib, const float* __restrict__ ghb,
                                             float* __restrict__ cb,
                                             float* __restrict__ psum, float* __restrict__ psqs, int N) {
  int tx = threadIdx.x & 127, ty = threadIdx.x >> 7;
  int n0 = blockIdx.x * 128;
  float s = 0.f, ss = 0.f;
  for (int r = ty; r < 128; r += 4) {
    int n = n0 + r;
    if (n >= N) break;
    size_t bi = (size_t)n * 384 + tx;
    float ir = gib[bi], iz = gib[bi + 128], in_ = gib[bi + 256];
    float hr = ghb[bi], hz = ghb[bi + 128], hn_ = ghb[bi + 256];
    float cv = cb[(size_t)n * 128 + tx];
    float rr = 1.f / (1.f + expf(-(ir + hr)));
    float z  = 1.f / (1.f + expf(-(iz + hz)));
    float nn = tanhf(in_ + rr * hn_);
    float v = (1.f - z) * nn + z * cv;
    cb[(size_t)n * 128 + tx] = v;
    s += v; ss += v * v;
  }
  __shared__ float sd[2][4][128];
  sd[0][ty][tx] = s; sd[1][ty][tx] = ss;
  __syncthreads();
  if (ty == 0) {
    s  = sd[0][0][tx] + sd[0][1][tx] + sd[0][2][tx] + sd[0][3][tx];
    ss = sd[1][0][tx] + sd[1][1][tx] + sd[1][2][tx] + sd[1][3][tx];
    atomicAdd(&psum[tx], s);
    atomicAdd(&psqs[tx], ss);
  }
}

// ---------------- BN apply ----------------
// MODE: 0 plain; 1 w=max(mx,v)->mx; 2 relu; 3 mx=v. STATS: stats of w.
template<int MODE, int STATS>
__global__ __launch_bounds__(512) void k_bn_apply(const float* __restrict__ x, int ldx,
                                                  const float* __restrict__ psum, const float* __restrict__ psqs,
                                                  const float* __restrict__ gamma, const float* __restrict__ beta,
                                                  float invN,
                                                  unsigned short* __restrict__ yb, float* __restrict__ yf,
                                                  float* __restrict__ mx,
                                                  float* __restrict__ npsum, float* __restrict__ npsqs,
                                                  int N, int D, int R) {
  __shared__ float cA[256], cB[256];
  int t = threadIdx.x;
  if (t < D) {
    float m = psum[t] * invN;
    float var = psqs[t] * invN - m * m;
    float a = gamma[t] * rsqrtf(var + EPSBN);
    cA[t] = a; cB[t] = beta[t] - m * a;
  }
  __syncthreads();
  int TY = 512 / D;
  int tx = t % D, ty = t / D;
  int n0 = blockIdx.x * R;
  float s = 0.f, ss = 0.f;
  for (int r = ty; r < R; r += TY) {
    int n = n0 + r;
    if (n >= N) break;
    float v = x[(size_t)n * ldx + tx] * cA[tx] + cB[tx];
    if (MODE == 2) v = fmaxf(v, 0.f);
    float w = v;
    if (MODE == 1) {
      size_t mi = (size_t)n * D + tx;
      w = fmaxf(mx[mi], v);
      mx[mi] = w;
    } else if (MODE == 3) {
      mx[(size_t)n * D + tx] = v;
    }
    if (yb) yb[(size_t)n * D + tx] = f2b(v);
    if (yf) yf[(size_t)n * D + tx] = v;
    if (STATS) { s += w; ss += w * w; }
  }
  if (STATS) {
    __shared__ float sd[2][4][256];
    sd[0][ty][tx] = s; sd[1][ty][tx] = ss;
    __syncthreads();
    if (ty == 0) {
      for (int q = 1; q < TY; ++q) { s += sd[0][q][tx]; ss += sd[1][q][tx]; }
      atomicAdd(&npsum[tx], s);
      atomicAdd(&npsqs[tx], ss);
    }
  }
}

// ---------------- final matvec ----------------
__global__ __launch_bounds__(256) void k_matvec(const float* __restrict__ y, const float* __restrict__ W2,
                                                const float* __restrict__ b2, float* __restrict__ out, int N) {
  int t = blockIdx.x * 256 + threadIdx.x;
  int row = t >> 6, lane = t & 63;
  if (row >= N) return;
  const float* yr = y + (size_t)row * 256;
  float s = 0.f;
#pragma unroll
  for (int k = 0; k < 4; ++k) s += yr[lane + 64 * k] * W2[lane + 64 * k];
#pragma unroll
  for (int off = 32; off > 0; off >>= 1) s += __shfl_down(s, off);
  if (lane == 0) out[row] = s + b2[0];
}

// ---------------- host orchestration ----------------
extern "C" void kernel_launch(void* const* d_in, const int* in_sizes, int n_in,
                              void* d_out, int out_size, void* d_ws, size_t ws_size,
                              hipStream_t stream) {
  const float* x    = (const float*)d_in[0];
  const int*   ei   = (const int*)d_in[1];
  const float* W_in = (const float*)d_in[2];
  const float* b_in = (const float*)d_in[3];
  const float* g0   = (const float*)d_in[4];
  const float* be0  = (const float*)d_in[5];
  const float* W_g  = (const float*)d_in[6];
  const float* b_g  = (const float*)d_in[7];
  const float* W_ih = (const float*)d_in[8];
  const float* W_hh = (const float*)d_in[9];
  const float* b_ih = (const float*)d_in[10];
  const float* b_hh = (const float*)d_in[11];
  const float* g_c  = (const float*)d_in[12];
  const float* be_c = (const float*)d_in[13];
  const float* g_o  = (const float*)d_in[14];
  const float* be_o = (const float*)d_in[15];
  const float* W1   = (const float*)d_in[16];
  const float* b1   = (const float*)d_in[17];
  const float* g1   = (const float*)d_in[18];
  const float* be1  = (const float*)d_in[19];
  const float* W2   = (const float*)d_in[20];
  const float* b2   = (const float*)d_in[21];

  const int N = in_sizes[0] / 128;   // 30000
  const int E = in_sizes[1] / 2;     // 480000
  const int ND = N * 128;
  const float invN = 1.0f / (float)N;

  float* p   = (float*)d_ws;
  float* gib = p; p += (size_t)N * 384;
  float* ghb = p; p += (size_t)N * 384;
  float* cb  = p; p += ND;
  float* mx  = p; p += ND;
  float* dis = p; p += ((N + 255) & ~255);
  float* stats = p; p += 8 * 512;
  float* fbias = p; p += 512;
  float* csr_nrm = p; p += E;
  int*   degi    = (int*)p; p += ((N + 255) & ~255);
  int*   rowptr  = (int*)p; p += ((N + 1 + 255) & ~255);
  int*   cursor  = (int*)p; p += ((N + 255) & ~255);
  int*   bsum    = (int*)p; p += 256;
  int*   csr_src = (int*)p; p += E;
  unsigned short* h_bf    = (unsigned short*)p;      // [N][128] post-BN hidden
  unsigned short* hp_bf   = h_bf + (size_t)ND;       // [N][128] conv input rows
  unsigned short* cb_bf   = hp_bf + (size_t)ND;      // [N][128] conv output
  unsigned short* fusedBT = cb_bf + (size_t)ND;      // [512][128]
  unsigned short* BThh    = fusedBT + 512 * 128;     // [384][128]
  unsigned short* BTin    = BThh + 384 * 128;        // [128][128]
  unsigned short* BT1     = BTin + 128 * 128;        // [256][128]

  float* ps0 = stats;
  float* psc[5];
  for (int i = 0; i < 5; ++i) psc[i] = stats + 512 * (1 + i);
  float* pso = stats + 512 * 6;
  float* ps1 = stats + 512 * 7;

  dim3 blk(256);
  int rb = (N + 127) / 128;
  int NBLK = (N + 255) / 256;

  // ---- preprocessing ----
  hipMemsetAsync(degi, 0, (size_t)N * sizeof(int), stream);
  hipMemsetAsync(stats, 0, 8 * 512 * sizeof(float), stream);
  k_count_deg<<<(E + 255) / 256, blk, 0, stream>>>(ei + E, degi, E);
  k_scan_p1<<<NBLK, blk, 0, stream>>>(degi, rowptr, bsum, dis, N);
  k_scan_p2<<<1, blk, 0, stream>>>(bsum, NBLK);
  k_scan_p3<<<(N + 256) / 256, blk, 0, stream>>>(rowptr, cursor, bsum, N, E);
  k_csr_fill<<<(E + 255) / 256, blk, 0, stream>>>(ei, ei + E, dis, cursor, csr_src, csr_nrm, E);
  k_wprep<<<(164352 + 255) / 256, blk, 0, stream>>>(W_g, W_ih, W_hh, W_in, W1, b_ih,
                                                    fusedBT, BThh, BTin, BT1, fbias);

  // ---- input layer: relu(x@W_in+b_in) -> gib[:,0:128] (ld 384), stats ps0 ----
  k_mmx<0, 1, 0><<<dim3(1, rb), blk, 0, stream>>>(x, BTin, b_in, gib, nullptr, ps0, ps0 + 256, N, 128, 384, 1);
  k_bn_apply<3, 0><<<(N + 127) / 128, 512, 0, stream>>>(gib, 384, ps0, ps0 + 256, g0, be0, invN,
                                                        h_bf, nullptr, mx, nullptr, nullptr, N, 128, 128);

  for (int it = 0; it < 5; ++it) {
    // fused GEMM: col0 -> hp_bf (bf16), cols 128..511 -> gib (f32, ld 384)
    k_mmx<1, 0, 1><<<dim3(4, rb), blk, 0, stream>>>(h_bf, fusedBT, fbias, gib, hp_bf, nullptr, nullptr, N, 128, 384, 0);
    // GCN aggregate from bf16 rows
    k_gcn_gather<<<(N * 32 + 255) / 256, blk, 0, stream>>>(rowptr, csr_src, csr_nrm, dis, hp_bf, b_g, cb, cb_bf, N);
    // gh = cb @ W_hh^T -> ghb (ld 384)
    k_mmx<1, 0, 0><<<dim3(3, rb), blk, 0, stream>>>(cb_bf, BThh, b_hh, ghb, nullptr, nullptr, nullptr, N, 128, 384, 0);
    // GRU gates: cb <- new hidden (in place), stats psc[it]
    k_gru<<<(N + 127) / 128, 512, 0, stream>>>(gib, ghb, cb, psc[it], psc[it] + 256, N);
    // BN + running max
    if (it < 4)
      k_bn_apply<1, 0><<<(N + 127) / 128, 512, 0, stream>>>(cb, 128, psc[it], psc[it] + 256, g_c, be_c, invN,
                                                            h_bf, nullptr, mx, nullptr, nullptr, N, 128, 128);
    else
      k_bn_apply<1, 1><<<(N + 127) / 128, 512, 0, stream>>>(cb, 128, psc[it], psc[it] + 256, g_c, be_c, invN,
                                                            h_bf, nullptr, mx, pso, pso + 256, N, 128, 128);
  }

  // ---- output BN on mx -> h_bf ----
  k_bn_apply<0, 0><<<(N + 127) / 128, 512, 0, stream>>>(mx, 128, pso, pso + 256, g_o, be_o, invN,
                                                        h_bf, nullptr, nullptr, nullptr, nullptr, N, 128, 128);
  // ---- encoder GEMM -> ghb (ld 384, cols 0..255), stats ps1 ----
  k_mmx<1, 1, 0><<<dim3(2, rb), blk, 0, stream>>>(h_bf, BT1, b1, ghb, nullptr, ps1, ps1 + 256, N, 128, 384, 0);
  // BN + relu -> gib (packed ld 256)
  k_bn_apply<2, 0><<<(N + 63) / 64, 512, 0, stream>>>(ghb, 384, ps1, ps1 + 256, g1, be1, invN,
                                                      nullptr, gib, nullptr, nullptr, nullptr, N, 256, 64);
  k_matvec<<<(N * 64 + 255) / 256, blk, 0, stream>>>(gib, W2, b2, (float*)d_out, N);
}

// Round 6
// 774.149 us; speedup vs baseline: 7.2598x; 1.0506x over previous
//
#include <hip/hip_runtime.h>
#include <cmath>

#define EPSBN 1e-5f

typedef __attribute__((ext_vector_type(8))) short short8v;
typedef __attribute__((ext_vector_type(4))) short short4v;
typedef __attribute__((ext_vector_type(4))) float f32x4;

__device__ inline unsigned short f2b(float x) {
  union { float f; unsigned int u; } v; v.f = x;
  unsigned int b = v.u;
  return (unsigned short)((b + 0x7FFFu + ((b >> 16) & 1u)) >> 16);
}
__device__ inline float b2f(unsigned short x) {
  union { unsigned int u; float f; } v; v.u = ((unsigned int)x) << 16;
  return v.f;
}

// ---------------- fused weight prep + zero-init (single kernel) ----------------
__global__ __launch_bounds__(256) void k_wprep(const float* __restrict__ W_g, const float* __restrict__ W_ih,
                                               const float* __restrict__ W_hh, const float* __restrict__ W_in,
                                               const float* __restrict__ W1, const float* __restrict__ b_ih,
                                               unsigned short* __restrict__ fusedBT, unsigned short* __restrict__ BThh,
                                               unsigned short* __restrict__ BTin, unsigned short* __restrict__ BT1,
                                               float* __restrict__ fbias, float* __restrict__ stats,
                                               int* __restrict__ degi, int N) {
  int i = blockIdx.x * 256 + threadIdx.x;
  if (i < 16384) {
    int k = i >> 7, m = i & 127;
    fusedBT[m * 128 + k] = f2b(W_g[i]);
  } else if (i < 65536) {
    int j = i - 16384;
    fusedBT[16384 + j] = f2b(W_ih[j]);
  } else if (i < 114688) {
    int j = i - 65536;
    BThh[j] = f2b(W_hh[j]);
  } else if (i < 131072) {
    int j = i - 114688;
    int k = j >> 7, m = j & 127;
    BTin[m * 128 + k] = f2b(W_in[j]);
  } else if (i < 163840) {
    int j = i - 131072;
    int k = j >> 8, m = j & 255;
    BT1[m * 128 + k] = f2b(W1[j]);
  } else if (i < 164352) {
    int j = i - 163840;
    fbias[j] = (j < 128) ? 0.f : b_ih[j - 128];
  } else if (i < 168448) {
    stats[i - 164352] = 0.f;
  } else if (i < 168448 + N) {
    degi[i - 168448] = 0;
  }
}

// ---------------- graph preprocessing ----------------
__global__ __launch_bounds__(256) void k_count_deg(const int* __restrict__ dst, int* __restrict__ deg, int E) {
  int i = blockIdx.x * 256 + threadIdx.x;
  if (i < E) atomicAdd(&deg[dst[i]], 1);
}

__global__ __launch_bounds__(256) void k_scan_p1(const int* __restrict__ deg, int* __restrict__ rowptr,
                                                 int* __restrict__ bsum, float* __restrict__ dis, int N) {
  __shared__ int sd[256];
  int t = threadIdx.x;
  int i = blockIdx.x * 256 + t;
  int v = (i < N) ? deg[i] : 0;
  if (i < N) dis[i] = rsqrtf((float)(v + 1));
  sd[t] = v;
  __syncthreads();
  for (int off = 1; off < 256; off <<= 1) {
    int u = (t >= off) ? sd[t - off] : 0;
    __syncthreads();
    sd[t] += u;
    __syncthreads();
  }
  if (i < N) rowptr[i] = sd[t] - v;
  if (t == 255) bsum[blockIdx.x] = sd[255];
}

__global__ void k_scan_p2(int* __restrict__ bsum, int NBLK) {
  __shared__ int sd[256];
  int t = threadIdx.x;
  int v = (t < NBLK) ? bsum[t] : 0;
  sd[t] = v;
  __syncthreads();
  for (int off = 1; off < 256; off <<= 1) {
    int u = (t >= off) ? sd[t - off] : 0;
    __syncthreads();
    sd[t] += u;
    __syncthreads();
  }
  if (t < NBLK) bsum[t] = sd[t] - v;
}

__global__ __launch_bounds__(256) void k_scan_p3(int* __restrict__ rowptr, int* __restrict__ cursor,
                                                 const int* __restrict__ bsum, int N, int E) {
  int i = blockIdx.x * 256 + threadIdx.x;
  if (i < N) {
    int v = rowptr[i] + bsum[blockIdx.x];
    rowptr[i] = v;
    cursor[i] = v;
  } else if (i == N) {
    rowptr[N] = E;
  }
}

__global__ __launch_bounds__(256) void k_csr_fill(const int* __restrict__ src, const int* __restrict__ dst,
                                                  int* __restrict__ cursor, int* __restrict__ csr_src, int E) {
  int e = blockIdx.x * 256 + threadIdx.x;
  if (e >= E) return;
  int s = src[e], d = dst[e];
  int pos = atomicAdd(&cursor[d], 1);
  csr_src[pos] = s;
}

// ---------------- bf16 MFMA matmul ----------------
// C = A[N,128] @ BT^T, BT is [M][128] bf16. Block tile 128x128, K=128,
// 4 waves (2x2 of 64x64). LDS XOR-swizzle byte ^= (row&7)<<4.
// SPLIT: col-block 0 -> Csplit bf16 ld128; other cols -> Co at col-128.
// OBF: Co is bf16 (else f32), stride ldC.
// BNA: during A staging apply y = cA[k]*a + cB[k] (coefA=[cA(128)|cB(128)]).
template<int ABF, int STATS, int SPLIT, int OBF, int BNA>
__global__ __launch_bounds__(256) void k_mmx(const void* __restrict__ Ap, const unsigned short* __restrict__ BT,
                                             const float* __restrict__ bias,
                                             void* __restrict__ Co, unsigned short* __restrict__ Csplit,
                                             const float* __restrict__ coefA,
                                             float* __restrict__ psum, float* __restrict__ psqs,
                                             int N, int ldA, int ldC, int relu)
{
  __shared__ unsigned short As[128 * 128];
  __shared__ unsigned short Bs[128 * 128];
  char* Asb = (char*)As;
  char* Bsb = (char*)Bs;
  int tid = threadIdx.x;
  int brow = blockIdx.y * 128, bcol = blockIdx.x * 128;

#pragma unroll
  for (int p = 0; p < 8; ++p) {
    int idx = p * 256 + tid;
    int r = idx >> 4, ch = idx & 15;
    int arow = brow + r;
    short8v v = {0, 0, 0, 0, 0, 0, 0, 0};
    if (ABF) {
      if (arow < N) v = *(const short8v*)((const unsigned short*)Ap + (size_t)arow * ldA + ch * 8);
      if (BNA) {
#pragma unroll
        for (int j = 0; j < 8; ++j) {
          int k = ch * 8 + j;
          float f = b2f((unsigned short)v[j]) * coefA[k] + coefA[128 + k];
          v[j] = (short)f2b(f);
        }
      }
    } else {
      if (arow < N) {
        const float* a = (const float*)Ap + (size_t)arow * ldA + ch * 8;
        f32x4 x0 = *(const f32x4*)a;
        f32x4 x1 = *(const f32x4*)(a + 4);
        v[0] = (short)f2b(x0[0]); v[1] = (short)f2b(x0[1]);
        v[2] = (short)f2b(x0[2]); v[3] = (short)f2b(x0[3]);
        v[4] = (short)f2b(x1[0]); v[5] = (short)f2b(x1[1]);
        v[6] = (short)f2b(x1[2]); v[7] = (short)f2b(x1[3]);
      }
    }
    *(short8v*)(Asb + r * 256 + ((ch * 16) ^ ((r & 7) << 4))) = v;
  }
#pragma unroll
  for (int p = 0; p < 8; ++p) {
    int idx = p * 256 + tid;
    int r = idx >> 4, ch = idx & 15;
    short8v v = *(const short8v*)(BT + (size_t)(bcol + r) * 128 + ch * 8);
    *(short8v*)(Bsb + r * 256 + ((ch * 16) ^ ((r & 7) << 4))) = v;
  }
  __syncthreads();

  int w = tid >> 6, l = tid & 63;
  int wm = (w >> 1) * 64, wn = (w & 1) * 64;
  int lg = l >> 4, lr = l & 15;
  f32x4 acc[4][4] = {};

#pragma unroll
  for (int ks = 0; ks < 4; ++ks) {
    int kb = ks * 64 + lg * 8;
    short8v a[4], b[4];
#pragma unroll
    for (int mt = 0; mt < 4; ++mt) {
      int r = wm + mt * 16 + lr;
      short4v lo = *(const short4v*)(Asb + r * 256 + (kb ^ ((r & 7) << 4)));
      short4v hi = *(const short4v*)(Asb + r * 256 + ((kb + 32) ^ ((r & 7) << 4)));
      a[mt] = __builtin_shufflevector(lo, hi, 0, 1, 2, 3, 4, 5, 6, 7);
    }
#pragma unroll
    for (int nt = 0; nt < 4; ++nt) {
      int r = wn + nt * 16 + lr;
      short4v lo = *(const short4v*)(Bsb + r * 256 + (kb ^ ((r & 7) << 4)));
      short4v hi = *(const short4v*)(Bsb + r * 256 + ((kb + 32) ^ ((r & 7) << 4)));
      b[nt] = __builtin_shufflevector(lo, hi, 0, 1, 2, 3, 4, 5, 6, 7);
    }
#pragma unroll
    for (int mt = 0; mt < 4; ++mt)
#pragma unroll
      for (int nt = 0; nt < 4; ++nt)
        acc[mt][nt] = __builtin_amdgcn_mfma_f32_16x16x32_bf16(a[mt], b[nt], acc[mt][nt], 0, 0, 0);
  }

  float sc[4] = {0.f, 0.f, 0.f, 0.f}, scc[4] = {0.f, 0.f, 0.f, 0.f};
  bool bfdest = SPLIT && (bcol == 0);
#pragma unroll
  for (int mt = 0; mt < 4; ++mt) {
#pragma unroll
    for (int nt = 0; nt < 4; ++nt) {
      int col = bcol + wn + nt * 16 + lr;
      float bv = bias ? bias[col] : 0.f;
#pragma unroll
      for (int r4 = 0; r4 < 4; ++r4) {
        int row = brow + wm + mt * 16 + lg * 4 + r4;
        if (row < N) {
          float v = acc[mt][nt][r4] + bv;
          if (relu) v = fmaxf(v, 0.f);
          if (bfdest) {
            Csplit[(size_t)row * 128 + col] = f2b(v);
          } else {
            int cc = SPLIT ? (col - 128) : col;
            if (OBF) ((unsigned short*)Co)[(size_t)row * ldC + cc] = f2b(v);
            else ((float*)Co)[(size_t)row * ldC + cc] = v;
          }
          if (STATS) { sc[nt] += v; scc[nt] += v * v; }
        }
      }
    }
  }
  if (STATS) {
#pragma unroll
    for (int nt = 0; nt < 4; ++nt) {
      float s = sc[nt], ss = scc[nt];
      s += __shfl_xor(s, 16); s += __shfl_xor(s, 32);
      ss += __shfl_xor(ss, 16); ss += __shfl_xor(ss, 32);
      if (lg == 0) {
        int col = bcol + wn + nt * 16 + lr;
        atomicAdd(&psum[col], s);
        atomicAdd(&psqs[col], ss);
      }
    }
  }
}

// ---------------- GCN gather (CSR, bf16 rows, on-the-fly norm) ----------------
__global__ __launch_bounds__(256) void k_gcn_gather(const int* __restrict__ rowptr, const int* __restrict__ csr_src,
                                                    const float* __restrict__ dis,
                                                    const unsigned short* __restrict__ hp,
                                                    const float* __restrict__ bg,
                                                    float* __restrict__ c, unsigned short* __restrict__ cbf, int N) {
  int t = blockIdx.x * 256 + threadIdx.x;
  int g = t >> 5, lane = t & 31;
  if (g >= N) return;
  int off = lane << 2;
  float dd = dis[g];
  float w0 = dd * dd;
  float4 acc = *(const float4*)(bg + off);
  short4v hv = *(const short4v*)(hp + ((size_t)g << 7) + off);
  acc.x += w0 * b2f((unsigned short)hv[0]);
  acc.y += w0 * b2f((unsigned short)hv[1]);
  acc.z += w0 * b2f((unsigned short)hv[2]);
  acc.w += w0 * b2f((unsigned short)hv[3]);
  int beg = rowptr[g], end = rowptr[g + 1];
  int j = beg;
  for (; j + 3 < end; j += 4) {
    int s0 = csr_src[j], s1 = csr_src[j + 1], s2 = csr_src[j + 2], s3 = csr_src[j + 3];
    float n0 = dis[s0] * dd, n1 = dis[s1] * dd, n2 = dis[s2] * dd, n3 = dis[s3] * dd;
    short4v v0 = *(const short4v*)(hp + ((size_t)s0 << 7) + off);
    short4v v1 = *(const short4v*)(hp + ((size_t)s1 << 7) + off);
    short4v v2 = *(const short4v*)(hp + ((size_t)s2 << 7) + off);
    short4v v3 = *(const short4v*)(hp + ((size_t)s3 << 7) + off);
    acc.x += n0 * b2f((unsigned short)v0[0]) + n1 * b2f((unsigned short)v1[0]) + n2 * b2f((unsigned short)v2[0]) + n3 * b2f((unsigned short)v3[0]);
    acc.y += n0 * b2f((unsigned short)v0[1]) + n1 * b2f((unsigned short)v1[1]) + n2 * b2f((unsigned short)v2[1]) + n3 * b2f((unsigned short)v3[1]);
    acc.z += n0 * b2f((unsigned short)v0[2]) + n1 * b2f((unsigned short)v1[2]) + n2 * b2f((unsigned short)v2[2]) + n3 * b2f((unsigned short)v3[2]);
    acc.w += n0 * b2f((unsigned short)v0[3]) + n1 * b2f((unsigned short)v1[3]) + n2 * b2f((unsigned short)v2[3]) + n3 * b2f((unsigned short)v3[3]);
  }
  for (; j < end; ++j) {
    int s0 = csr_src[j];
    float n0 = dis[s0] * dd;
    short4v v0 = *(const short4v*)(hp + ((size_t)s0 << 7) + off);
    acc.x += n0 * b2f((unsigned short)v0[0]);
    acc.y += n0 * b2f((unsigned short)v0[1]);
    acc.z += n0 * b2f((unsigned short)v0[2]);
    acc.w += n0 * b2f((unsigned short)v0[3]);
  }
  *(float4*)(c + ((size_t)g << 7) + off) = acc;
  short4v b;
  b[0] = (short)f2b(acc.x); b[1] = (short)f2b(acc.y);
  b[2] = (short)f2b(acc.z); b[3] = (short)f2b(acc.w);
  *(short4v*)(cbf + ((size_t)g << 7) + off) = b;
}

// ---------------- GRU gates (bf16 gate inputs, fused BN stats) ----------------
__global__ __launch_bounds__(512) void k_gru(const unsigned short* __restrict__ gib,
                                             const unsigned short* __restrict__ ghb,
                                             float* __restrict__ cb,
                                             float* __restrict__ psum, float* __restrict__ psqs, int N) {
  int tx = threadIdx.x & 127, ty = threadIdx.x >> 7;
  int n0 = blockIdx.x * 128;
  float s = 0.f, ss = 0.f;
  for (int r = ty; r < 128; r += 4) {
    int n = n0 + r;
    if (n >= N) break;
    size_t bi = (size_t)n * 384 + tx;
    float ir = b2f(gib[bi]), iz = b2f(gib[bi + 128]), in_ = b2f(gib[bi + 256]);
    float hr = b2f(ghb[bi]), hz = b2f(ghb[bi + 128]), hn_ = b2f(ghb[bi + 256]);
    float cv = cb[(size_t)n * 128 + tx];
    float rr = 1.f / (1.f + expf(-(ir + hr)));
    float z  = 1.f / (1.f + expf(-(iz + hz)));
    float nn = tanhf(in_ + rr * hn_);
    float v = (1.f - z) * nn + z * cv;
    cb[(size_t)n * 128 + tx] = v;
    s += v; ss += v * v;
  }
  __shared__ float sd[2][4][128];
  sd[0][ty][tx] = s; sd[1][ty][tx] = ss;
  __syncthreads();
  if (ty == 0) {
    s  = sd[0][0][tx] + sd[0][1][tx] + sd[0][2][tx] + sd[0][3][tx];
    ss = sd[1][0][tx] + sd[1][1][tx] + sd[1][2][tx] + sd[1][3][tx];
    atomicAdd(&psum[tx], s);
    atomicAdd(&psqs[tx], ss);
  }
}

// ---------------- BN apply (bf16 outputs + bf16 running max) ----------------
// MODE: 1 w=max(mx,v)->mx; 3 mx=v. STATS: stats of w -> npsum/npsqs.
template<int MODE, int STATS>
__global__ __launch_bounds__(512) void k_bn_apply(const float* __restrict__ x, int ldx,
                                                  const float* __restrict__ psum, const float* __restrict__ psqs,
                                                  const float* __restrict__ gamma, const float* __restrict__ beta,
                                                  float invN,
                                                  unsigned short* __restrict__ yb, unsigned short* __restrict__ mx,
                                                  float* __restrict__ npsum, float* __restrict__ npsqs,
                                                  int N, int R) {
  __shared__ float cA[128], cB[128];
  int t = threadIdx.x;
  if (t < 128) {
    float m = psum[t] * invN;
    float var = psqs[t] * invN - m * m;
    float a = gamma[t] * rsqrtf(var + EPSBN);
    cA[t] = a; cB[t] = beta[t] - m * a;
  }
  __syncthreads();
  int tx = t & 127, ty = t >> 7;
  int n0 = blockIdx.x * R;
  float s = 0.f, ss = 0.f;
  for (int r = ty; r < R; r += 4) {
    int n = n0 + r;
    if (n >= N) break;
    size_t i = (size_t)n * 128 + tx;
    float v = x[(size_t)n * ldx + tx] * cA[tx] + cB[tx];
    float w = v;
    if (MODE == 1) {
      w = fmaxf(b2f(mx[i]), v);
      mx[i] = f2b(w);
    } else {
      mx[i] = f2b(v);
    }
    yb[i] = f2b(v);
    if (STATS) { s += w; ss += w * w; }
  }
  if (STATS) {
    __shared__ float sd[2][4][128];
    sd[0][ty][tx] = s; sd[1][ty][tx] = ss;
    __syncthreads();
    if (ty == 0) {
      for (int q = 1; q < 4; ++q) { s += sd[0][q][tx]; ss += sd[1][q][tx]; }
      atomicAdd(&npsum[tx], s);
      atomicAdd(&npsqs[tx], ss);
    }
  }
}

// ---------------- BN coef ----------------
__global__ void k_coef(const float* __restrict__ psum, const float* __restrict__ psqs,
                       const float* __restrict__ gamma, const float* __restrict__ beta,
                       float invN, float* __restrict__ coef, int D) {
  int t = threadIdx.x;
  if (t < D) {
    float m = psum[t] * invN;
    float var = psqs[t] * invN - m * m;
    float a = gamma[t] * rsqrtf(var + EPSBN);
    coef[t] = a;
    coef[D + t] = beta[t] - m * a;
  }
}

// ---------------- final matvec with fused BN+relu ----------------
__global__ __launch_bounds__(256) void k_matvec(const unsigned short* __restrict__ y, const float* __restrict__ coef,
                                                const float* __restrict__ W2, const float* __restrict__ b2,
                                                float* __restrict__ out, int N) {
  int t = blockIdx.x * 256 + threadIdx.x;
  int row = t >> 6, lane = t & 63;
  if (row >= N) return;
  const unsigned short* yr = y + (size_t)row * 384;
  float s = 0.f;
#pragma unroll
  for (int k = 0; k < 4; ++k) {
    int c = lane + 64 * k;
    float v = fmaxf(b2f(yr[c]) * coef[c] + coef[256 + c], 0.f);
    s += v * W2[c];
  }
#pragma unroll
  for (int off = 32; off > 0; off >>= 1) s += __shfl_down(s, off);
  if (lane == 0) out[row] = s + b2[0];
}

// ---------------- host orchestration ----------------
extern "C" void kernel_launch(void* const* d_in, const int* in_sizes, int n_in,
                              void* d_out, int out_size, void* d_ws, size_t ws_size,
                              hipStream_t stream) {
  const float* x    = (const float*)d_in[0];
  const int*   ei   = (const int*)d_in[1];
  const float* W_in = (const float*)d_in[2];
  const float* b_in = (const float*)d_in[3];
  const float* g0   = (const float*)d_in[4];
  const float* be0  = (const float*)d_in[5];
  const float* W_g  = (const float*)d_in[6];
  const float* b_g  = (const float*)d_in[7];
  const float* W_ih = (const float*)d_in[8];
  const float* W_hh = (const float*)d_in[9];
  const float* b_ih = (const float*)d_in[10];
  const float* b_hh = (const float*)d_in[11];
  const float* g_c  = (const float*)d_in[12];
  const float* be_c = (const float*)d_in[13];
  const float* g_o  = (const float*)d_in[14];
  const float* be_o = (const float*)d_in[15];
  const float* W1   = (const float*)d_in[16];
  const float* b1   = (const float*)d_in[17];
  const float* g1   = (const float*)d_in[18];
  const float* be1  = (const float*)d_in[19];
  const float* W2   = (const float*)d_in[20];
  const float* b2   = (const float*)d_in[21];

  const int N = in_sizes[0] / 128;   // 30000
  const int E = in_sizes[1] / 2;     // 480000
  const int ND = N * 128;
  const float invN = 1.0f / (float)N;

  float* p   = (float*)d_ws;
  float* cb  = p; p += ND;               // f32: input-GEMM staging / conv out / GRU hidden
  float* dis = p; p += ((N + 255) & ~255);
  float* stats = p; p += 8 * 512;
  float* fbias = p; p += 512;
  float* coefO = p; p += 256;
  float* coef1 = p; p += 512;
  int*   degi    = (int*)p; p += ((N + 255) & ~255);
  int*   rowptr  = (int*)p; p += ((N + 1 + 255) & ~255);
  int*   cursor  = (int*)p; p += ((N + 255) & ~255);
  int*   bsum    = (int*)p; p += 256;
  int*   csr_src = (int*)p; p += E;
  unsigned short* h_bf    = (unsigned short*)p;      // [N][128] post-BN hidden
  unsigned short* hp_bf   = h_bf + (size_t)ND;       // [N][128] conv input rows
  unsigned short* cb_bf   = hp_bf + (size_t)ND;      // [N][128] conv output
  unsigned short* mx_bf   = cb_bf + (size_t)ND;      // [N][128] running max
  unsigned short* gib_bf  = mx_bf + (size_t)ND;      // [N][384] gi
  unsigned short* ghb_bf  = gib_bf + (size_t)N * 384;// [N][384] gh / y1
  unsigned short* fusedBT = ghb_bf + (size_t)N * 384;// [512][128]
  unsigned short* BThh    = fusedBT + 512 * 128;     // [384][128]
  unsigned short* BTin    = BThh + 384 * 128;        // [128][128]
  unsigned short* BT1     = BTin + 128 * 128;        // [256][128]

  float* ps0 = stats;
  float* psc[5];
  for (int i = 0; i < 5; ++i) psc[i] = stats + 512 * (1 + i);
  float* pso = stats + 512 * 6;
  float* ps1 = stats + 512 * 7;

  dim3 blk(256);
  int rb = (N + 127) / 128;
  int NBLK = (N + 255) / 256;
  int bnb = (N + 127) / 128;

  // ---- preprocessing ----
  k_wprep<<<(168448 + N + 255) / 256, blk, 0, stream>>>(W_g, W_ih, W_hh, W_in, W1, b_ih,
                                                        fusedBT, BThh, BTin, BT1, fbias, stats, degi, N);
  k_count_deg<<<(E + 255) / 256, blk, 0, stream>>>(ei + E, degi, E);
  k_scan_p1<<<NBLK, blk, 0, stream>>>(degi, rowptr, bsum, dis, N);
  k_scan_p2<<<1, blk, 0, stream>>>(bsum, NBLK);
  k_scan_p3<<<(N + 256) / 256, blk, 0, stream>>>(rowptr, cursor, bsum, N, E);
  k_csr_fill<<<(E + 255) / 256, blk, 0, stream>>>(ei, ei + E, cursor, csr_src, E);

  // ---- input layer: relu(x@W_in+b_in) -> cb (f32 ld128), stats ps0 ----
  k_mmx<0, 1, 0, 0, 0><<<dim3(1, rb), blk, 0, stream>>>(x, BTin, b_in, cb, nullptr, nullptr,
                                                        ps0, ps0 + 256, N, 128, 128, 1);
  k_bn_apply<3, 0><<<bnb, 512, 0, stream>>>(cb, 128, ps0, ps0 + 256, g0, be0, invN,
                                            h_bf, mx_bf, nullptr, nullptr, N, 128);

  for (int it = 0; it < 5; ++it) {
    // fused GEMM: col0 -> hp_bf (bf16), cols 128..511 -> gib_bf (bf16 ld384)
    k_mmx<1, 0, 1, 1, 0><<<dim3(4, rb), blk, 0, stream>>>(h_bf, fusedBT, fbias, gib_bf, hp_bf, nullptr,
                                                          nullptr, nullptr, N, 128, 384, 0);
    // GCN aggregate
    k_gcn_gather<<<(N * 32 + 255) / 256, blk, 0, stream>>>(rowptr, csr_src, dis, hp_bf, b_g, cb, cb_bf, N);
    // gh = cb @ W_hh^T -> ghb_bf (bf16 ld384)
    k_mmx<1, 0, 0, 1, 0><<<dim3(3, rb), blk, 0, stream>>>(cb_bf, BThh, b_hh, ghb_bf, nullptr, nullptr,
                                                          nullptr, nullptr, N, 128, 384, 0);
    // GRU gates: cb <- new hidden (in place), stats psc[it]
    k_gru<<<bnb, 512, 0, stream>>>(gib_bf, ghb_bf, cb, psc[it], psc[it] + 256, N);
    // BN + running max
    if (it < 4)
      k_bn_apply<1, 0><<<bnb, 512, 0, stream>>>(cb, 128, psc[it], psc[it] + 256, g_c, be_c, invN,
                                                h_bf, mx_bf, nullptr, nullptr, N, 128);
    else
      k_bn_apply<1, 1><<<bnb, 512, 0, stream>>>(cb, 128, psc[it], psc[it] + 256, g_c, be_c, invN,
                                                h_bf, mx_bf, pso, pso + 256, N, 128);
  }

  // ---- tail: coefO -> encoder GEMM (BN fused in staging) -> coef1 -> matvec ----
  k_coef<<<1, 128, 0, stream>>>(pso, pso + 256, g_o, be_o, invN, coefO, 128);
  k_mmx<1, 1, 0, 1, 1><<<dim3(2, rb), blk, 0, stream>>>(mx_bf, BT1, b1, ghb_bf, nullptr, coefO,
                                                        ps1, ps1 + 256, N, 128, 384, 0);
  k_coef<<<1, 256, 0, stream>>>(ps1, ps1 + 256, g1, be1, invN, coef1, 256);
  k_matvec<<<(N * 64 + 255) / 256, blk, 0, stream>>>(ghb_bf, coef1, W2, b2, (float*)d_out, N);
}